// Round 3
// baseline (906.371 us; speedup 1.0000x reference)
//
#include <hip/hip_runtime.h>
#include <hip/hip_bf16.h>
#include <stdint.h>

#define FDIM 128

typedef short bf16x8 __attribute__((ext_vector_type(8)));
typedef float f32x4 __attribute__((ext_vector_type(4)));

__device__ __forceinline__ unsigned short f2bf(float f) {
    union { float f; unsigned int u; } v; v.f = f;
    unsigned int r = v.u + 0x7FFFu + ((v.u >> 16) & 1u);
    return (unsigned short)(r >> 16);
}
__device__ __forceinline__ unsigned int pack2bf(float a, float b) {
    return (unsigned int)f2bf(a) | ((unsigned int)f2bf(b) << 16);
}
__device__ __forceinline__ float bflo(unsigned int u) {
    union { unsigned int u; float f; } v; v.u = u << 16; return v.f;
}
__device__ __forceinline__ float bfhi(unsigned int u) {
    union { unsigned int u; float f; } v; v.u = u & 0xFFFF0000u; return v.f;
}
__device__ __forceinline__ float bf2f(unsigned short u) {
    union { unsigned int u; float f; } v; v.u = (unsigned int)u << 16; return v.f;
}

// ---------------- prep: pre-swizzled bf16 B-matrices ----------------
// bt1[n][k] n<128, k<256: k<128 -> wNext[k][n] else wPrev[k-128][n]
// bt2 PERMUTED rows: original row n (gate g=n>>7, feature fl=n&127) stored at
//   nn = (fl>>4)*64 + g*16 + (fl&15)   -> wave w owns rows [w*64, w*64+64) = 4 gates x its 16 feats
__global__ void prep_kernel(const float* __restrict__ wNext, const float* __restrict__ wPrev,
                            const float* __restrict__ gk, const float* __restrict__ gr,
                            const float* __restrict__ gb, const float* __restrict__ gamma,
                            const float* __restrict__ beta, const float* __restrict__ mean,
                            const float* __restrict__ var,
                            unsigned short* __restrict__ bt1, unsigned short* __restrict__ bt2,
                            float* __restrict__ bias2, float* __restrict__ bnscale,
                            float* __restrict__ bnshift)
{
    int t = blockIdx.x * blockDim.x + threadIdx.x;
    if (t < 32768) {
        int n = t >> 8, k = t & 255;
        float v = (k < 128) ? wNext[k * 128 + n] : wPrev[(k - 128) * 128 + n];
        unsigned int byte = (unsigned)n * 512u + (((unsigned)(k * 2)) ^ (((unsigned)(n & 15)) << 4));
        *(unsigned short*)((unsigned char*)bt1 + byte) = f2bf(v);
    } else if (t < 32768 + 131072) {
        int e = t - 32768;
        int n = e >> 8, k = e & 255;
        float v;
        if (n < 256)      v = (k < 128) ? gk[k * 384 + n] : gr[(k - 128) * 384 + n];
        else if (n < 384) v = (k < 128) ? gk[k * 384 + n] : 0.f;
        else              v = (k < 128) ? 0.f : gr[(k - 128) * 384 + (n - 128)];
        int g = n >> 7, fl = n & 127;
        int nn = ((fl >> 4) << 6) + (g << 4) + (fl & 15);
        unsigned int byte = (unsigned)nn * 512u + (((unsigned)(k * 2)) ^ (((unsigned)(nn & 15)) << 4));
        *(unsigned short*)((unsigned char*)bt2 + byte) = f2bf(v);
    } else if (t < 32768 + 131072 + 512) {
        int n = t - (32768 + 131072);
        float v;
        if (n < 256)      v = gb[n] + gb[384 + n];
        else if (n < 384) v = gb[n];
        else              v = gb[384 + (n - 128)];
        bias2[n] = v;
    } else if (t < 32768 + 131072 + 512 + 128) {
        int f = t - (32768 + 131072 + 512);
        float s = gamma[f] * rsqrtf(var[f] + 1e-3f);
        bnscale[f] = s;
        bnshift[f] = beta[f] - mean[f] * s;
    }
}

// ---------------- x_convert: x f32 -> pre-swizzled bf16 rows (256B/row) ----------------
__global__ __launch_bounds__(256) void x_convert(const float* __restrict__ x,
                                                 unsigned short* __restrict__ xbf, int Nn)
{
    const int total = Nn * 32;
    const float4* x4 = (const float4*)x;
    for (int t = blockIdx.x * 256 + threadIdx.x; t < total; t += gridDim.x * 256) {
        int m = t >> 5, l = t & 31;
        float4 v = x4[t];
        unsigned int lo = pack2bf(v.x, v.y), hi = pack2bf(v.z, v.w);
        unsigned int byte = (unsigned)m * 256u + (((unsigned)(l * 8)) ^ (((unsigned)(m & 15)) << 4));
        uint2 pk; pk.x = lo; pk.y = hi;
        *(uint2*)((unsigned char*)xbf + byte) = pk;
    }
}

// ---------------- g_gather: high-occupancy gather+sum, writes [sumNext|sumPrev] bf16 swizzled ----------------
__global__ __launch_bounds__(256) void g_gather(const unsigned short* __restrict__ xbf,
                                                const int* __restrict__ pprev,
                                                const int* __restrict__ pnext,
                                                unsigned short* __restrict__ s_ws, int Nn)
{
    const int lane = threadIdx.x & 63;
    const int wg = blockIdx.x * 4 + (threadIdx.x >> 6);
    const int nw = gridDim.x * 4;
    const unsigned int o = (unsigned)lane * 4u;
    const unsigned char* xb = (const unsigned char*)xbf;
    for (int nb = wg * 4; nb < Nn; nb += nw * 4) {
#pragma unroll
        for (int u = 0; u < 4; u++) {
            int n = nb + u;
            if (n < Nn) {
                int i0 = pnext[4 * n + 1], i1 = pnext[4 * n + 3];
                int j0 = pprev[4 * n + 1], j1 = pprev[4 * n + 3];
                unsigned int a0 = *(const unsigned int*)(xb + (size_t)i0 * 256u + (o ^ (((unsigned)(i0 & 15)) << 4)));
                unsigned int a1 = *(const unsigned int*)(xb + (size_t)i1 * 256u + (o ^ (((unsigned)(i1 & 15)) << 4)));
                unsigned int b0 = *(const unsigned int*)(xb + (size_t)j0 * 256u + (o ^ (((unsigned)(j0 & 15)) << 4)));
                unsigned int b1 = *(const unsigned int*)(xb + (size_t)j1 * 256u + (o ^ (((unsigned)(j1 & 15)) << 4)));
                float nx0 = bflo(a0) + bflo(a1), nx1 = bfhi(a0) + bfhi(a1);
                float px0 = bflo(b0) + bflo(b1), px1 = bfhi(b0) + bfhi(b1);
                unsigned int swz = ((unsigned)(n & 15)) << 4;
                unsigned char* row = (unsigned char*)s_ws + (size_t)n * 512u;
                *(unsigned int*)(row + (o ^ swz)) = pack2bf(nx0, nx1);
                *(unsigned int*)(row + 256u + (o ^ swz)) = pack2bf(px0, px1);
            }
        }
    }
}

// ---------------- m_fused: persistent blocks, B in registers, double-buffered A-stage ----------------
// LDS: S0[0,32K) S1[32K,64K) X0[64K,80K) X1[80K,96K) A[96K,112K)
__global__ __launch_bounds__(512, 2) void m_fused(
    const unsigned short* __restrict__ s_ws, const unsigned short* __restrict__ xbf,
    const unsigned short* __restrict__ bt1, const unsigned short* __restrict__ bt2p,
    const float* __restrict__ bvec, const float* __restrict__ bnscale,
    const float* __restrict__ bnshift, const float* __restrict__ bias2,
    float* __restrict__ out, int Nn)
{
    __shared__ __align__(16) unsigned char lds[114688];
    const int tid = threadIdx.x, wid = tid >> 6, lane = tid & 63;
    const int col0 = lane & 15, kq = lane >> 4;
    const unsigned int rs = (unsigned)col0 << 4;

    // persistent per-wave B fragments (B1: 32 regs, B2: 128 regs)
    const unsigned char* bt1b = (const unsigned char*)bt1;
    const unsigned char* bt2b = (const unsigned char*)bt2p;
    bf16x8 b1[8], b2[4][8];
#pragma unroll
    for (int kk = 0; kk < 8; kk++)
        b1[kk] = *(const bf16x8*)(bt1b + (unsigned)(wid * 16 + col0) * 512u +
                                  (((unsigned)(kk * 64 + kq * 16)) ^ rs));
#pragma unroll
    for (int g = 0; g < 4; g++)
#pragma unroll
        for (int kk = 0; kk < 8; kk++)
            b2[g][kk] = *(const bf16x8*)(bt2b + (unsigned)(wid * 64 + g * 16 + col0) * 512u +
                                         (((unsigned)(kk * 64 + kq * 16)) ^ rs));

    const int f = wid * 16 + col0;
    const float bb = bvec[f], sc = bnscale[f], sh = bnshift[f];
    const float cz = bias2[f], cr = bias2[128 + f], cxh = bias2[256 + f], crh = bias2[384 + f];

    const unsigned char* sB = (const unsigned char*)s_ws;
    const unsigned char* xB = (const unsigned char*)xbf;
    const int tiles = (Nn + 63) >> 6;

#define STAGE(tt, pp) do {                                                                 \
    size_t sg_ = (size_t)(tt) * 32768u + (unsigned)(wid * 4096) + (unsigned)(lane * 16);   \
    size_t xg_ = (size_t)(tt) * 16384u + (unsigned)(wid * 2048) + (unsigned)(lane * 16);   \
    _Pragma("unroll")                                                                      \
    for (int j_ = 0; j_ < 4; j_++)                                                         \
        __builtin_amdgcn_global_load_lds(                                                  \
            (const __attribute__((address_space(1))) unsigned int*)(sB + sg_ + j_ * 1024), \
            (__attribute__((address_space(3))) unsigned int*)(lds + (pp) * 32768 + wid * 4096 + j_ * 1024), \
            16, 0, 0);                                                                     \
    _Pragma("unroll")                                                                      \
    for (int j_ = 0; j_ < 2; j_++)                                                         \
        __builtin_amdgcn_global_load_lds(                                                  \
            (const __attribute__((address_space(1))) unsigned int*)(xB + xg_ + j_ * 1024), \
            (__attribute__((address_space(3))) unsigned int*)(lds + 65536 + (pp) * 16384 + wid * 2048 + j_ * 1024), \
            16, 0, 0);                                                                     \
} while (0)

    // prologue: stage first tile into buffer 0
    STAGE(blockIdx.x, 0);

    int p = 0;
    for (int t = blockIdx.x; t < tiles; t += gridDim.x) {
        // all prior LDS reads consumed by each wave pre-barrier; stage(t) drained here
        asm volatile("s_waitcnt vmcnt(0)" ::: "memory");
        __builtin_amdgcn_s_barrier();
        __builtin_amdgcn_sched_barrier(0);

        int tn = t + (int)gridDim.x;
        if (tn < tiles) STAGE(tn, p ^ 1);

        const unsigned char* S = lds + p * 32768;
        const unsigned char* X = lds + 65536 + p * 16384;
        unsigned char* A = lds + 98304;

        // ---- GEMM1: acc1[m] (64 rows x wave's 16 cols) ----
        f32x4 acc1[4];
#pragma unroll
        for (int m = 0; m < 4; m++) acc1[m] = (f32x4){0.f, 0.f, 0.f, 0.f};
#pragma unroll
        for (int kk = 0; kk < 8; kk++) {
            bf16x8 a0 = *(const bf16x8*)(S + (unsigned)(0 * 16 + col0) * 512u + (((unsigned)(kk * 64 + kq * 16)) ^ rs));
            bf16x8 a1 = *(const bf16x8*)(S + (unsigned)(1 * 16 + col0) * 512u + (((unsigned)(kk * 64 + kq * 16)) ^ rs));
            bf16x8 a2 = *(const bf16x8*)(S + (unsigned)(2 * 16 + col0) * 512u + (((unsigned)(kk * 64 + kq * 16)) ^ rs));
            bf16x8 a3 = *(const bf16x8*)(S + (unsigned)(3 * 16 + col0) * 512u + (((unsigned)(kk * 64 + kq * 16)) ^ rs));
            acc1[0] = __builtin_amdgcn_mfma_f32_16x16x32_bf16(a0, b1[kk], acc1[0], 0, 0, 0);
            acc1[1] = __builtin_amdgcn_mfma_f32_16x16x32_bf16(a1, b1[kk], acc1[1], 0, 0, 0);
            acc1[2] = __builtin_amdgcn_mfma_f32_16x16x32_bf16(a2, b1[kk], acc1[2], 0, 0, 0);
            acc1[3] = __builtin_amdgcn_mfma_f32_16x16x32_bf16(a3, b1[kk], acc1[3], 0, 0, 0);
        }

        // ---- epilogue1: + b + x, relu, BN -> aBuf (bf16 swizzled) ----
        const int base = t * 64;
#pragma unroll
        for (int m = 0; m < 4; m++) {
#pragma unroll
            for (int i = 0; i < 4; i++) {
                int r = m * 16 + kq * 4 + i;
                if (base + r < Nn) {
                    unsigned int sw = ((unsigned)(r & 15)) << 4;
                    float xv = bf2f(*(const unsigned short*)(X + (unsigned)r * 256u + (((unsigned)(f * 2)) ^ sw)));
                    float v = acc1[m][i] + bb + xv;
                    v = fmaxf(v, 0.f) * sc + sh;
                    *(unsigned short*)(A + (unsigned)r * 256u + (((unsigned)(f * 2)) ^ sw)) = f2bf(v);
                }
            }
        }
        asm volatile("s_waitcnt lgkmcnt(0)" ::: "memory");
        __builtin_amdgcn_s_barrier();
        __builtin_amdgcn_sched_barrier(0);

        // ---- GEMM2: A2 = [a | x], B in registers, acc2[m][gate] ----
        f32x4 acc2[4][4];
#pragma unroll
        for (int m = 0; m < 4; m++)
#pragma unroll
            for (int g = 0; g < 4; g++) acc2[m][g] = (f32x4){0.f, 0.f, 0.f, 0.f};
#pragma unroll
        for (int kk = 0; kk < 8; kk++) {
            bf16x8 a2f[4];
#pragma unroll
            for (int m = 0; m < 4; m++) {
                if (kk < 4)
                    a2f[m] = *(const bf16x8*)(A + (unsigned)(m * 16 + col0) * 256u +
                                              (((unsigned)(kk * 64 + kq * 16)) ^ rs));
                else
                    a2f[m] = *(const bf16x8*)(X + (unsigned)(m * 16 + col0) * 256u +
                                              (((unsigned)((kk - 4) * 64 + kq * 16)) ^ rs));
            }
#pragma unroll
            for (int m = 0; m < 4; m++)
#pragma unroll
                for (int g = 0; g < 4; g++)
                    acc2[m][g] = __builtin_amdgcn_mfma_f32_16x16x32_bf16(a2f[m], b2[g][kk], acc2[m][g], 0, 0, 0);
        }

        // ---- GRU epilogue ----
#pragma unroll
        for (int m = 0; m < 4; m++) {
#pragma unroll
            for (int i = 0; i < 4; i++) {
                int r = m * 16 + kq * 4 + i;
                int grow = base + r;
                if (grow < Nn) {
                    float zs = acc2[m][0][i] + cz;
                    float rsum = acc2[m][1][i] + cr;
                    float xh = acc2[m][2][i] + cxh;
                    float rh = acc2[m][3][i] + crh;
                    float z = 1.f / (1.f + __expf(-zs));
                    float rr = 1.f / (1.f + __expf(-rsum));
                    float u = xh + rr * rh;
                    float au = fabsf(u);
                    float tt = __expf(2.f * au);
                    float th = 1.f - 2.f / (tt + 1.f);
                    float hh = (u >= 0.f) ? th : -th;
                    unsigned int sw = ((unsigned)(r & 15)) << 4;
                    float xv = bf2f(*(const unsigned short*)(X + (unsigned)r * 256u + (((unsigned)(f * 2)) ^ sw)));
                    out[(size_t)grow * FDIM + f] = z * xv + (1.f - z) * hh;
                }
            }
        }
        p ^= 1;
    }
#undef STAGE
}

extern "C" void kernel_launch(void* const* d_in, const int* in_sizes, int n_in,
                              void* d_out, int out_size, void* d_ws, size_t ws_size,
                              hipStream_t stream)
{
    const float* x      = (const float*)d_in[0];
    const int*   pprev  = (const int*)d_in[1];
    const int*   pnext  = (const int*)d_in[2];
    const float* wNext  = (const float*)d_in[3];
    const float* wPrev  = (const float*)d_in[4];
    const float* b      = (const float*)d_in[5];
    const float* gk     = (const float*)d_in[6];
    const float* gr     = (const float*)d_in[7];
    const float* gb     = (const float*)d_in[8];
    const float* gamma  = (const float*)d_in[9];
    const float* beta   = (const float*)d_in[10];
    const float* mean   = (const float*)d_in[11];
    const float* var    = (const float*)d_in[12];
    float* out = (float*)d_out;
    const int Nn = in_sizes[0] / FDIM;

    // ws layout: s_ws (N*512B) | xbf (N*256B) | bt1 (64KB) | bt2 (256KB) | bias2 | bnscale | bnshift
    unsigned char* ws = (unsigned char*)d_ws;
    unsigned short* s_ws = (unsigned short*)(ws + 0);
    size_t off_x  = (size_t)Nn * 512u;
    size_t off_bt = off_x + (size_t)Nn * 256u;
    unsigned short* xbf   = (unsigned short*)(ws + off_x);
    unsigned short* bt1   = (unsigned short*)(ws + off_bt);
    unsigned short* bt2   = (unsigned short*)(ws + off_bt + 65536);
    float* bias2          = (float*)(ws + off_bt + 327680);
    float* bnscale        = (float*)(ws + off_bt + 327680 + 2048);
    float* bnshift        = (float*)(ws + off_bt + 327680 + 2048 + 512);

    prep_kernel<<<643, 256, 0, stream>>>(wNext, wPrev, gk, gr, gb, gamma, beta, mean, var,
                                         bt1, bt2, bias2, bnscale, bnshift);
    x_convert<<<2048, 256, 0, stream>>>(x, xbf, Nn);
    g_gather<<<2048, 256, 0, stream>>>(xbf, pprev, pnext, s_ws, Nn);
    m_fused<<<256, 512, 0, stream>>>(s_ws, xbf, bt1, bt2, b, bnscale, bnshift, bias2, out, Nn);
}

// Round 4
// 794.755 us; speedup vs baseline: 1.1404x; 1.1404x over previous
//
#include <hip/hip_runtime.h>
#include <hip/hip_bf16.h>
#include <stdint.h>

#define FDIM 128

typedef short bf16x8 __attribute__((ext_vector_type(8)));
typedef float f32x4 __attribute__((ext_vector_type(4)));

__device__ __forceinline__ unsigned short f2bf(float f) {
    union { float f; unsigned int u; } v; v.f = f;
    unsigned int r = v.u + 0x7FFFu + ((v.u >> 16) & 1u);
    return (unsigned short)(r >> 16);
}
__device__ __forceinline__ unsigned int pack2bf(float a, float b) {
    return (unsigned int)f2bf(a) | ((unsigned int)f2bf(b) << 16);
}
__device__ __forceinline__ float bflo(unsigned int u) {
    union { unsigned int u; float f; } v; v.u = u << 16; return v.f;
}
__device__ __forceinline__ float bfhi(unsigned int u) {
    union { unsigned int u; float f; } v; v.u = u & 0xFFFF0000u; return v.f;
}
__device__ __forceinline__ float bf2f(unsigned short u) {
    union { unsigned int u; float f; } v; v.u = (unsigned int)u << 16; return v.f;
}

// ---------------- prep: pre-swizzled bf16 B-matrices ----------------
// bt1[n][k] n<128, k<256: k<128 -> wNext[k][n] else wPrev[k-128][n]
// bt2 PERMUTED rows: original row n (gate g=n>>7, feature fl=n&127) stored at
//   nn = (fl>>4)*64 + g*16 + (fl&15)   -> wave w owns rows [w*64, w*64+64)
// gates: g=0:z  g=1:r  g=2:xh (only k<128 nonzero)  g=3:rh (only k>=128 nonzero)
__global__ void prep_kernel(const float* __restrict__ wNext, const float* __restrict__ wPrev,
                            const float* __restrict__ gk, const float* __restrict__ gr,
                            const float* __restrict__ gb, const float* __restrict__ gamma,
                            const float* __restrict__ beta, const float* __restrict__ mean,
                            const float* __restrict__ var,
                            unsigned short* __restrict__ bt1, unsigned short* __restrict__ bt2,
                            float* __restrict__ bias2, float* __restrict__ bnscale,
                            float* __restrict__ bnshift)
{
    int t = blockIdx.x * blockDim.x + threadIdx.x;
    if (t < 32768) {
        int n = t >> 8, k = t & 255;
        float v = (k < 128) ? wNext[k * 128 + n] : wPrev[(k - 128) * 128 + n];
        unsigned int byte = (unsigned)n * 512u + (((unsigned)(k * 2)) ^ (((unsigned)(n & 15)) << 4));
        *(unsigned short*)((unsigned char*)bt1 + byte) = f2bf(v);
    } else if (t < 32768 + 131072) {
        int e = t - 32768;
        int n = e >> 8, k = e & 255;
        float v;
        if (n < 256)      v = (k < 128) ? gk[k * 384 + n] : gr[(k - 128) * 384 + n];
        else if (n < 384) v = (k < 128) ? gk[k * 384 + n] : 0.f;
        else              v = (k < 128) ? 0.f : gr[(k - 128) * 384 + (n - 128)];
        int g = n >> 7, fl = n & 127;
        int nn = ((fl >> 4) << 6) + (g << 4) + (fl & 15);
        unsigned int byte = (unsigned)nn * 512u + (((unsigned)(k * 2)) ^ (((unsigned)(nn & 15)) << 4));
        *(unsigned short*)((unsigned char*)bt2 + byte) = f2bf(v);
    } else if (t < 32768 + 131072 + 512) {
        int n = t - (32768 + 131072);
        float v;
        if (n < 256)      v = gb[n] + gb[384 + n];
        else if (n < 384) v = gb[n];
        else              v = gb[384 + (n - 128)];
        bias2[n] = v;
    } else if (t < 32768 + 131072 + 512 + 128) {
        int f = t - (32768 + 131072 + 512);
        float s = gamma[f] * rsqrtf(var[f] + 1e-3f);
        bnscale[f] = s;
        bnshift[f] = beta[f] - mean[f] * s;
    }
}

// ---------------- x_convert: x f32 -> pre-swizzled bf16 rows (256B/row) ----------------
__global__ __launch_bounds__(256) void x_convert(const float* __restrict__ x,
                                                 unsigned short* __restrict__ xbf, int Nn)
{
    const int total = Nn * 32;
    const float4* x4 = (const float4*)x;
    for (int t = blockIdx.x * 256 + threadIdx.x; t < total; t += gridDim.x * 256) {
        int m = t >> 5, l = t & 31;
        float4 v = x4[t];
        unsigned int lo = pack2bf(v.x, v.y), hi = pack2bf(v.z, v.w);
        unsigned int byte = (unsigned)m * 256u + (((unsigned)(l * 8)) ^ (((unsigned)(m & 15)) << 4));
        uint2 pk; pk.x = lo; pk.y = hi;
        *(uint2*)((unsigned char*)xbf + byte) = pk;
    }
}

// ---------------- g_gather: high-occupancy gather+sum, writes [sumNext|sumPrev] bf16 swizzled ----------------
__global__ __launch_bounds__(256) void g_gather(const unsigned short* __restrict__ xbf,
                                                const int* __restrict__ pprev,
                                                const int* __restrict__ pnext,
                                                unsigned short* __restrict__ s_ws, int Nn)
{
    const int lane = threadIdx.x & 63;
    const int wg = blockIdx.x * 4 + (threadIdx.x >> 6);
    const int nw = gridDim.x * 4;
    const unsigned int o = (unsigned)lane * 4u;
    const unsigned char* xb = (const unsigned char*)xbf;
    for (int nb = wg * 4; nb < Nn; nb += nw * 4) {
#pragma unroll
        for (int u = 0; u < 4; u++) {
            int n = nb + u;
            if (n < Nn) {
                int i0 = pnext[4 * n + 1], i1 = pnext[4 * n + 3];
                int j0 = pprev[4 * n + 1], j1 = pprev[4 * n + 3];
                unsigned int a0 = *(const unsigned int*)(xb + (size_t)i0 * 256u + (o ^ (((unsigned)(i0 & 15)) << 4)));
                unsigned int a1 = *(const unsigned int*)(xb + (size_t)i1 * 256u + (o ^ (((unsigned)(i1 & 15)) << 4)));
                unsigned int b0 = *(const unsigned int*)(xb + (size_t)j0 * 256u + (o ^ (((unsigned)(j0 & 15)) << 4)));
                unsigned int b1 = *(const unsigned int*)(xb + (size_t)j1 * 256u + (o ^ (((unsigned)(j1 & 15)) << 4)));
                float nx0 = bflo(a0) + bflo(a1), nx1 = bfhi(a0) + bfhi(a1);
                float px0 = bflo(b0) + bflo(b1), px1 = bfhi(b0) + bfhi(b1);
                unsigned int swz = ((unsigned)(n & 15)) << 4;
                unsigned char* row = (unsigned char*)s_ws + (size_t)n * 512u;
                *(unsigned int*)(row + (o ^ swz)) = pack2bf(nx0, nx1);
                *(unsigned int*)(row + 256u + (o ^ swz)) = pack2bf(px0, px1);
            }
        }
    }
}

// ---------------- m_fused: persistent blocks, sparse B2 in registers (96), counted vmcnt ----------------
// LDS: S0[0,32K) S1[32K,64K) X0[64K,80K) X1[80K,96K) A[96K,112K)
__global__ __launch_bounds__(512, 2) void m_fused(
    const unsigned short* __restrict__ s_ws, const unsigned short* __restrict__ xbf,
    const unsigned short* __restrict__ bt1, const unsigned short* __restrict__ bt2p,
    const float* __restrict__ bvec, const float* __restrict__ bnscale,
    const float* __restrict__ bnshift, const float* __restrict__ bias2,
    float* __restrict__ out, int Nn)
{
    __shared__ __align__(16) unsigned char lds[114688];
    const int tid = threadIdx.x, wid = tid >> 6, lane = tid & 63;
    const int col0 = lane & 15, kq = lane >> 4;
    const unsigned int rs = (unsigned)col0 << 4;

    // persistent per-wave B fragments: b1 32 regs, b2 96 regs (sparse xh/rh)
    const unsigned char* bt1b = (const unsigned char*)bt1;
    const unsigned char* bt2b = (const unsigned char*)bt2p;
    bf16x8 b1[8], b2z[8], b2r[8], b2xh[4], b2rh[4];
#pragma unroll
    for (int kk = 0; kk < 8; kk++)
        b1[kk] = *(const bf16x8*)(bt1b + (unsigned)(wid * 16 + col0) * 512u +
                                  (((unsigned)(kk * 64 + kq * 16)) ^ rs));
#pragma unroll
    for (int kk = 0; kk < 8; kk++)
        b2z[kk] = *(const bf16x8*)(bt2b + (unsigned)(wid * 64 + 0 + col0) * 512u +
                                   (((unsigned)(kk * 64 + kq * 16)) ^ rs));
#pragma unroll
    for (int kk = 0; kk < 8; kk++)
        b2r[kk] = *(const bf16x8*)(bt2b + (unsigned)(wid * 64 + 16 + col0) * 512u +
                                   (((unsigned)(kk * 64 + kq * 16)) ^ rs));
#pragma unroll
    for (int kk = 0; kk < 4; kk++)
        b2xh[kk] = *(const bf16x8*)(bt2b + (unsigned)(wid * 64 + 32 + col0) * 512u +
                                    (((unsigned)(kk * 64 + kq * 16)) ^ rs));
#pragma unroll
    for (int kk = 0; kk < 4; kk++)
        b2rh[kk] = *(const bf16x8*)(bt2b + (unsigned)(wid * 64 + 48 + col0) * 512u +
                                    (((unsigned)((kk + 4) * 64 + kq * 16)) ^ rs));

    const int f = wid * 16 + col0;
    const float bb = bvec[f], sc = bnscale[f], sh = bnshift[f];
    const float cz = bias2[f], cr = bias2[128 + f], cxh = bias2[256 + f], crh = bias2[384 + f];

    const unsigned char* sB = (const unsigned char*)s_ws;
    const unsigned char* xB = (const unsigned char*)xbf;
    const int tiles = (Nn + 63) >> 6;

#define STAGE(tt, pp) do {                                                                 \
    size_t sg_ = (size_t)(tt) * 32768u + (unsigned)(wid * 4096) + (unsigned)(lane * 16);   \
    size_t xg_ = (size_t)(tt) * 16384u + (unsigned)(wid * 2048) + (unsigned)(lane * 16);   \
    _Pragma("unroll")                                                                      \
    for (int j_ = 0; j_ < 4; j_++)                                                         \
        __builtin_amdgcn_global_load_lds(                                                  \
            (const __attribute__((address_space(1))) unsigned int*)(sB + sg_ + j_ * 1024), \
            (__attribute__((address_space(3))) unsigned int*)(lds + (pp) * 32768 + wid * 4096 + j_ * 1024), \
            16, 0, 0);                                                                     \
    _Pragma("unroll")                                                                      \
    for (int j_ = 0; j_ < 2; j_++)                                                         \
        __builtin_amdgcn_global_load_lds(                                                  \
            (const __attribute__((address_space(1))) unsigned int*)(xB + xg_ + j_ * 1024), \
            (__attribute__((address_space(3))) unsigned int*)(lds + 65536 + (pp) * 16384 + wid * 2048 + j_ * 1024), \
            16, 0, 0);                                                                     \
} while (0)

    // prologue: stage first tile into buffer 0
    STAGE(blockIdx.x, 0);

    int p = 0;
    for (int t = blockIdx.x; t < tiles; t += gridDim.x) {
        // drain this buffer's stage loads; allow previous iter's 16 out-stores to stay in flight
        asm volatile("s_waitcnt vmcnt(16)" ::: "memory");
        __builtin_amdgcn_s_barrier();
        __builtin_amdgcn_sched_barrier(0);

        int tn = t + (int)gridDim.x;
        if (tn < tiles) STAGE(tn, p ^ 1);

        const unsigned char* S = lds + p * 32768;
        const unsigned char* X = lds + 65536 + p * 16384;
        unsigned char* A = lds + 98304;

        // ---- GEMM1: acc1[m] (64 rows x wave's 16 cols) ----
        f32x4 acc1[4];
#pragma unroll
        for (int m = 0; m < 4; m++) acc1[m] = (f32x4){0.f, 0.f, 0.f, 0.f};
#pragma unroll
        for (int kk = 0; kk < 8; kk++) {
            bf16x8 a0 = *(const bf16x8*)(S + (unsigned)(0 * 16 + col0) * 512u + (((unsigned)(kk * 64 + kq * 16)) ^ rs));
            bf16x8 a1 = *(const bf16x8*)(S + (unsigned)(1 * 16 + col0) * 512u + (((unsigned)(kk * 64 + kq * 16)) ^ rs));
            bf16x8 a2 = *(const bf16x8*)(S + (unsigned)(2 * 16 + col0) * 512u + (((unsigned)(kk * 64 + kq * 16)) ^ rs));
            bf16x8 a3 = *(const bf16x8*)(S + (unsigned)(3 * 16 + col0) * 512u + (((unsigned)(kk * 64 + kq * 16)) ^ rs));
            acc1[0] = __builtin_amdgcn_mfma_f32_16x16x32_bf16(a0, b1[kk], acc1[0], 0, 0, 0);
            acc1[1] = __builtin_amdgcn_mfma_f32_16x16x32_bf16(a1, b1[kk], acc1[1], 0, 0, 0);
            acc1[2] = __builtin_amdgcn_mfma_f32_16x16x32_bf16(a2, b1[kk], acc1[2], 0, 0, 0);
            acc1[3] = __builtin_amdgcn_mfma_f32_16x16x32_bf16(a3, b1[kk], acc1[3], 0, 0, 0);
        }

        // ---- epilogue1: + b + x, relu, BN -> aBuf (bf16 swizzled) ----
        const int base = t * 64;
#pragma unroll
        for (int m = 0; m < 4; m++) {
#pragma unroll
            for (int i = 0; i < 4; i++) {
                int r = m * 16 + kq * 4 + i;
                if (base + r < Nn) {
                    unsigned int sw = ((unsigned)(r & 15)) << 4;
                    float xv = bf2f(*(const unsigned short*)(X + (unsigned)r * 256u + (((unsigned)(f * 2)) ^ sw)));
                    float v = acc1[m][i] + bb + xv;
                    v = fmaxf(v, 0.f) * sc + sh;
                    *(unsigned short*)(A + (unsigned)r * 256u + (((unsigned)(f * 2)) ^ sw)) = f2bf(v);
                }
            }
        }
        asm volatile("s_waitcnt lgkmcnt(0)" ::: "memory");
        __builtin_amdgcn_s_barrier();
        __builtin_amdgcn_sched_barrier(0);

        // ---- GEMM2: A2 = [a (kk<4) | x (kk>=4)], sparse gates ----
        f32x4 az[4], ar[4], axh[4], arh[4];
#pragma unroll
        for (int m = 0; m < 4; m++) {
            az[m] = (f32x4){0.f, 0.f, 0.f, 0.f};
            ar[m] = (f32x4){0.f, 0.f, 0.f, 0.f};
            axh[m] = (f32x4){0.f, 0.f, 0.f, 0.f};
            arh[m] = (f32x4){0.f, 0.f, 0.f, 0.f};
        }
#pragma unroll
        for (int kk = 0; kk < 8; kk++) {
            bf16x8 a2f[4];
#pragma unroll
            for (int m = 0; m < 4; m++) {
                if (kk < 4)
                    a2f[m] = *(const bf16x8*)(A + (unsigned)(m * 16 + col0) * 256u +
                                              (((unsigned)(kk * 64 + kq * 16)) ^ rs));
                else
                    a2f[m] = *(const bf16x8*)(X + (unsigned)(m * 16 + col0) * 256u +
                                              (((unsigned)((kk - 4) * 64 + kq * 16)) ^ rs));
            }
#pragma unroll
            for (int m = 0; m < 4; m++) {
                az[m] = __builtin_amdgcn_mfma_f32_16x16x32_bf16(a2f[m], b2z[kk], az[m], 0, 0, 0);
                ar[m] = __builtin_amdgcn_mfma_f32_16x16x32_bf16(a2f[m], b2r[kk], ar[m], 0, 0, 0);
                if (kk < 4)
                    axh[m] = __builtin_amdgcn_mfma_f32_16x16x32_bf16(a2f[m], b2xh[kk], axh[m], 0, 0, 0);
                else
                    arh[m] = __builtin_amdgcn_mfma_f32_16x16x32_bf16(a2f[m], b2rh[kk - 4], arh[m], 0, 0, 0);
            }
        }

        // ---- GRU epilogue ----
#pragma unroll
        for (int m = 0; m < 4; m++) {
#pragma unroll
            for (int i = 0; i < 4; i++) {
                int r = m * 16 + kq * 4 + i;
                int grow = base + r;
                if (grow < Nn) {
                    float zs = az[m][i] + cz;
                    float rsum = ar[m][i] + cr;
                    float xh = axh[m][i] + cxh;
                    float rh = arh[m][i] + crh;
                    float z = 1.f / (1.f + __expf(-zs));
                    float rr = 1.f / (1.f + __expf(-rsum));
                    float u = xh + rr * rh;
                    float au = fabsf(u);
                    float tt = __expf(2.f * au);
                    float th = 1.f - 2.f / (tt + 1.f);
                    float hh = (u >= 0.f) ? th : -th;
                    unsigned int sw = ((unsigned)(r & 15)) << 4;
                    float xv = bf2f(*(const unsigned short*)(X + (unsigned)r * 256u + (((unsigned)(f * 2)) ^ sw)));
                    out[(size_t)grow * FDIM + f] = z * xv + (1.f - z) * hh;
                }
            }
        }
        p ^= 1;
    }
#undef STAGE
}

extern "C" void kernel_launch(void* const* d_in, const int* in_sizes, int n_in,
                              void* d_out, int out_size, void* d_ws, size_t ws_size,
                              hipStream_t stream)
{
    const float* x      = (const float*)d_in[0];
    const int*   pprev  = (const int*)d_in[1];
    const int*   pnext  = (const int*)d_in[2];
    const float* wNext  = (const float*)d_in[3];
    const float* wPrev  = (const float*)d_in[4];
    const float* b      = (const float*)d_in[5];
    const float* gk     = (const float*)d_in[6];
    const float* gr     = (const float*)d_in[7];
    const float* gb     = (const float*)d_in[8];
    const float* gamma  = (const float*)d_in[9];
    const float* beta   = (const float*)d_in[10];
    const float* mean   = (const float*)d_in[11];
    const float* var    = (const float*)d_in[12];
    float* out = (float*)d_out;
    const int Nn = in_sizes[0] / FDIM;

    // ws layout: s_ws (N*512B) | xbf (N*256B) | bt1 (64KB) | bt2 (256KB) | bias2 | bnscale | bnshift
    unsigned char* ws = (unsigned char*)d_ws;
    unsigned short* s_ws = (unsigned short*)(ws + 0);
    size_t off_x  = (size_t)Nn * 512u;
    size_t off_bt = off_x + (size_t)Nn * 256u;
    unsigned short* xbf   = (unsigned short*)(ws + off_x);
    unsigned short* bt1   = (unsigned short*)(ws + off_bt);
    unsigned short* bt2   = (unsigned short*)(ws + off_bt + 65536);
    float* bias2          = (float*)(ws + off_bt + 327680);
    float* bnscale        = (float*)(ws + off_bt + 327680 + 2048);
    float* bnshift        = (float*)(ws + off_bt + 327680 + 2048 + 512);

    prep_kernel<<<643, 256, 0, stream>>>(wNext, wPrev, gk, gr, gb, gamma, beta, mean, var,
                                         bt1, bt2, bias2, bnscale, bnshift);
    x_convert<<<2048, 256, 0, stream>>>(x, xbf, Nn);
    g_gather<<<2048, 256, 0, stream>>>(xbf, pprev, pnext, s_ws, Nn);
    m_fused<<<256, 512, 0, stream>>>(s_ws, xbf, bt1, bt2, b, bnscale, bnshift, bias2, out, Nn);
}

// Round 5
// 670.887 us; speedup vs baseline: 1.3510x; 1.1846x over previous
//
#include <hip/hip_runtime.h>
#include <hip/hip_bf16.h>
#include <stdint.h>

#define FDIM 128

typedef short bf16x8 __attribute__((ext_vector_type(8)));
typedef float f32x4 __attribute__((ext_vector_type(4)));

__device__ __forceinline__ unsigned short f2bf(float f) {
    union { float f; unsigned int u; } v; v.f = f;
    unsigned int r = v.u + 0x7FFFu + ((v.u >> 16) & 1u);
    return (unsigned short)(r >> 16);
}
__device__ __forceinline__ unsigned int pack2bf(float a, float b) {
    return (unsigned int)f2bf(a) | ((unsigned int)f2bf(b) << 16);
}
__device__ __forceinline__ float bflo(unsigned int u) {
    union { unsigned int u; float f; } v; v.u = u << 16; return v.f;
}
__device__ __forceinline__ float bfhi(unsigned int u) {
    union { unsigned int u; float f; } v; v.u = u & 0xFFFF0000u; return v.f;
}
__device__ __forceinline__ float bf2f(unsigned short u) {
    union { unsigned int u; float f; } v; v.u = (unsigned int)u << 16; return v.f;
}

// ---------------- prep: pre-swizzled bf16 B-matrices ----------------
// bt1[n][k] n<128, k<256: k<128 -> wNext[k][n] else wPrev[k-128][n]
// bt2 PERMUTED rows: original row n (gate g=n>>7, feature fl=n&127) stored at
//   nn = (fl>>4)*64 + g*16 + (fl&15)   -> wave w owns rows [w*64, w*64+64)
// gates: g=0:z  g=1:r  g=2:xh (only k<128 nonzero)  g=3:rh (only k>=128 nonzero)
__global__ void prep_kernel(const float* __restrict__ wNext, const float* __restrict__ wPrev,
                            const float* __restrict__ gk, const float* __restrict__ gr,
                            const float* __restrict__ gb, const float* __restrict__ gamma,
                            const float* __restrict__ beta, const float* __restrict__ mean,
                            const float* __restrict__ var,
                            unsigned short* __restrict__ bt1, unsigned short* __restrict__ bt2,
                            float* __restrict__ bias2, float* __restrict__ bnscale,
                            float* __restrict__ bnshift)
{
    int t = blockIdx.x * blockDim.x + threadIdx.x;
    if (t < 32768) {
        int n = t >> 8, k = t & 255;
        float v = (k < 128) ? wNext[k * 128 + n] : wPrev[(k - 128) * 128 + n];
        unsigned int byte = (unsigned)n * 512u + (((unsigned)(k * 2)) ^ (((unsigned)(n & 15)) << 4));
        *(unsigned short*)((unsigned char*)bt1 + byte) = f2bf(v);
    } else if (t < 32768 + 131072) {
        int e = t - 32768;
        int n = e >> 8, k = e & 255;
        float v;
        if (n < 256)      v = (k < 128) ? gk[k * 384 + n] : gr[(k - 128) * 384 + n];
        else if (n < 384) v = (k < 128) ? gk[k * 384 + n] : 0.f;
        else              v = (k < 128) ? 0.f : gr[(k - 128) * 384 + (n - 128)];
        int g = n >> 7, fl = n & 127;
        int nn = ((fl >> 4) << 6) + (g << 4) + (fl & 15);
        unsigned int byte = (unsigned)nn * 512u + (((unsigned)(k * 2)) ^ (((unsigned)(nn & 15)) << 4));
        *(unsigned short*)((unsigned char*)bt2 + byte) = f2bf(v);
    } else if (t < 32768 + 131072 + 512) {
        int n = t - (32768 + 131072);
        float v;
        if (n < 256)      v = gb[n] + gb[384 + n];
        else if (n < 384) v = gb[n];
        else              v = gb[384 + (n - 128)];
        bias2[n] = v;
    } else if (t < 32768 + 131072 + 512 + 128) {
        int f = t - (32768 + 131072 + 512);
        float s = gamma[f] * rsqrtf(var[f] + 1e-3f);
        bnscale[f] = s;
        bnshift[f] = beta[f] - mean[f] * s;
    }
}

// ---------------- x_convert: x f32 -> pre-swizzled bf16 rows (256B/row) ----------------
__global__ __launch_bounds__(256) void x_convert(const float* __restrict__ x,
                                                 unsigned short* __restrict__ xbf, int Nn)
{
    const int total = Nn * 32;
    const float4* x4 = (const float4*)x;
    for (int t = blockIdx.x * 256 + threadIdx.x; t < total; t += gridDim.x * 256) {
        int m = t >> 5, l = t & 31;
        float4 v = x4[t];
        unsigned int lo = pack2bf(v.x, v.y), hi = pack2bf(v.z, v.w);
        unsigned int byte = (unsigned)m * 256u + (((unsigned)(l * 8)) ^ (((unsigned)(m & 15)) << 4));
        uint2 pk; pk.x = lo; pk.y = hi;
        *(uint2*)((unsigned char*)xbf + byte) = pk;
    }
}

// ---------------- g_gather: high-occupancy gather+sum, writes [sumNext|sumPrev] bf16 swizzled ----------------
__global__ __launch_bounds__(256) void g_gather(const unsigned short* __restrict__ xbf,
                                                const int* __restrict__ pprev,
                                                const int* __restrict__ pnext,
                                                unsigned short* __restrict__ s_ws, int Nn)
{
    const int lane = threadIdx.x & 63;
    const int wg = blockIdx.x * 4 + (threadIdx.x >> 6);
    const int nw = gridDim.x * 4;
    const unsigned int o = (unsigned)lane * 4u;
    const unsigned char* xb = (const unsigned char*)xbf;
    for (int nb = wg * 4; nb < Nn; nb += nw * 4) {
#pragma unroll
        for (int u = 0; u < 4; u++) {
            int n = nb + u;
            if (n < Nn) {
                int i0 = pnext[4 * n + 1], i1 = pnext[4 * n + 3];
                int j0 = pprev[4 * n + 1], j1 = pprev[4 * n + 3];
                unsigned int a0 = *(const unsigned int*)(xb + (size_t)i0 * 256u + (o ^ (((unsigned)(i0 & 15)) << 4)));
                unsigned int a1 = *(const unsigned int*)(xb + (size_t)i1 * 256u + (o ^ (((unsigned)(i1 & 15)) << 4)));
                unsigned int b0 = *(const unsigned int*)(xb + (size_t)j0 * 256u + (o ^ (((unsigned)(j0 & 15)) << 4)));
                unsigned int b1 = *(const unsigned int*)(xb + (size_t)j1 * 256u + (o ^ (((unsigned)(j1 & 15)) << 4)));
                float nx0 = bflo(a0) + bflo(a1), nx1 = bfhi(a0) + bfhi(a1);
                float px0 = bflo(b0) + bflo(b1), px1 = bfhi(b0) + bfhi(b1);
                unsigned int swz = ((unsigned)(n & 15)) << 4;
                unsigned char* row = (unsigned char*)s_ws + (size_t)n * 512u;
                *(unsigned int*)(row + (o ^ swz)) = pack2bf(nx0, nx1);
                *(unsigned int*)(row + 256u + (o ^ swz)) = pack2bf(px0, px1);
            }
        }
    }
}

// ---------------- m_fused: persistent blocks, B resident (pinned), GEMM2 split in row-halves ----------------
// LDS: S0[0,32K) S1[32K,64K) X0[64K,80K) X1[80K,96K) A[96K,112K)
__attribute__((amdgpu_waves_per_eu(2, 2)))
__global__ __launch_bounds__(512) void m_fused(
    const unsigned short* __restrict__ s_ws, const unsigned short* __restrict__ xbf,
    const unsigned short* __restrict__ bt1, const unsigned short* __restrict__ bt2p,
    const float* __restrict__ bvec, const float* __restrict__ bnscale,
    const float* __restrict__ bnshift, const float* __restrict__ bias2,
    float* __restrict__ out, int Nn)
{
    __shared__ __align__(16) unsigned char lds[114688];
    const int tid = threadIdx.x, wid = tid >> 6, lane = tid & 63;
    const int col0 = lane & 15, kq = lane >> 4;
    const unsigned int rs = (unsigned)col0 << 4;

    // persistent per-wave B fragments: b1 32 regs, b2 96 regs (sparse xh/rh)
    const unsigned char* bt1b = (const unsigned char*)bt1;
    const unsigned char* bt2b = (const unsigned char*)bt2p;
    bf16x8 b1[8], b2z[8], b2r[8], b2xh[4], b2rh[4];
#pragma unroll
    for (int kk = 0; kk < 8; kk++)
        b1[kk] = *(const bf16x8*)(bt1b + (unsigned)(wid * 16 + col0) * 512u +
                                  (((unsigned)(kk * 64 + kq * 16)) ^ rs));
#pragma unroll
    for (int kk = 0; kk < 8; kk++)
        b2z[kk] = *(const bf16x8*)(bt2b + (unsigned)(wid * 64 + 0 + col0) * 512u +
                                   (((unsigned)(kk * 64 + kq * 16)) ^ rs));
#pragma unroll
    for (int kk = 0; kk < 8; kk++)
        b2r[kk] = *(const bf16x8*)(bt2b + (unsigned)(wid * 64 + 16 + col0) * 512u +
                                   (((unsigned)(kk * 64 + kq * 16)) ^ rs));
#pragma unroll
    for (int kk = 0; kk < 4; kk++)
        b2xh[kk] = *(const bf16x8*)(bt2b + (unsigned)(wid * 64 + 32 + col0) * 512u +
                                    (((unsigned)(kk * 64 + kq * 16)) ^ rs));
#pragma unroll
    for (int kk = 0; kk < 4; kk++)
        b2rh[kk] = *(const bf16x8*)(bt2b + (unsigned)(wid * 64 + 48 + col0) * 512u +
                                    (((unsigned)((kk + 4) * 64 + kq * 16)) ^ rs));

    // pin B fragments in VGPRs: asm output is non-rematerializable, so the
    // allocator cannot turn these loop-invariant loads into per-tile re-loads
#pragma unroll
    for (int kk = 0; kk < 8; kk++) {
        asm volatile("" : "+v"(b1[kk]));
        asm volatile("" : "+v"(b2z[kk]));
        asm volatile("" : "+v"(b2r[kk]));
    }
#pragma unroll
    for (int kk = 0; kk < 4; kk++) {
        asm volatile("" : "+v"(b2xh[kk]));
        asm volatile("" : "+v"(b2rh[kk]));
    }

    const int f = wid * 16 + col0;
    const float bb = bvec[f], sc = bnscale[f], sh = bnshift[f];
    const float cz = bias2[f], cr = bias2[128 + f], cxh = bias2[256 + f], crh = bias2[384 + f];

    const unsigned char* sB = (const unsigned char*)s_ws;
    const unsigned char* xB = (const unsigned char*)xbf;
    const int tiles = (Nn + 63) >> 6;

#define STAGE(tt, pp) do {                                                                 \
    size_t sg_ = (size_t)(tt) * 32768u + (unsigned)(wid * 4096) + (unsigned)(lane * 16);   \
    size_t xg_ = (size_t)(tt) * 16384u + (unsigned)(wid * 2048) + (unsigned)(lane * 16);   \
    _Pragma("unroll")                                                                      \
    for (int j_ = 0; j_ < 4; j_++)                                                         \
        __builtin_amdgcn_global_load_lds(                                                  \
            (const __attribute__((address_space(1))) unsigned int*)(sB + sg_ + j_ * 1024), \
            (__attribute__((address_space(3))) unsigned int*)(lds + (pp) * 32768 + wid * 4096 + j_ * 1024), \
            16, 0, 0);                                                                     \
    _Pragma("unroll")                                                                      \
    for (int j_ = 0; j_ < 2; j_++)                                                         \
        __builtin_amdgcn_global_load_lds(                                                  \
            (const __attribute__((address_space(1))) unsigned int*)(xB + xg_ + j_ * 1024), \
            (__attribute__((address_space(3))) unsigned int*)(lds + 65536 + (pp) * 16384 + wid * 2048 + j_ * 1024), \
            16, 0, 0);                                                                     \
} while (0)

    // prologue: stage first tile into buffer 0 and DRAIN (B loads + stage) — no race
    STAGE(blockIdx.x, 0);
    asm volatile("s_waitcnt vmcnt(0) lgkmcnt(0)" ::: "memory");
    __builtin_amdgcn_sched_barrier(0);
    __builtin_amdgcn_s_barrier();

    int p = 0;
    for (int t = blockIdx.x; t < tiles; t += gridDim.x) {
        int tn = t + (int)gridDim.x;
        if (tn < tiles) STAGE(tn, p ^ 1);

        const unsigned char* S = lds + p * 32768;
        const unsigned char* X = lds + 65536 + p * 16384;
        unsigned char* A = lds + 98304;

        // ---- GEMM1: acc1[m] (64 rows x wave's 16 cols) ----
        f32x4 acc1[4];
#pragma unroll
        for (int m = 0; m < 4; m++) acc1[m] = (f32x4){0.f, 0.f, 0.f, 0.f};
#pragma unroll
        for (int kk = 0; kk < 8; kk++) {
            bf16x8 a0 = *(const bf16x8*)(S + (unsigned)(0 * 16 + col0) * 512u + (((unsigned)(kk * 64 + kq * 16)) ^ rs));
            bf16x8 a1 = *(const bf16x8*)(S + (unsigned)(1 * 16 + col0) * 512u + (((unsigned)(kk * 64 + kq * 16)) ^ rs));
            bf16x8 a2 = *(const bf16x8*)(S + (unsigned)(2 * 16 + col0) * 512u + (((unsigned)(kk * 64 + kq * 16)) ^ rs));
            bf16x8 a3 = *(const bf16x8*)(S + (unsigned)(3 * 16 + col0) * 512u + (((unsigned)(kk * 64 + kq * 16)) ^ rs));
            acc1[0] = __builtin_amdgcn_mfma_f32_16x16x32_bf16(a0, b1[kk], acc1[0], 0, 0, 0);
            acc1[1] = __builtin_amdgcn_mfma_f32_16x16x32_bf16(a1, b1[kk], acc1[1], 0, 0, 0);
            acc1[2] = __builtin_amdgcn_mfma_f32_16x16x32_bf16(a2, b1[kk], acc1[2], 0, 0, 0);
            acc1[3] = __builtin_amdgcn_mfma_f32_16x16x32_bf16(a3, b1[kk], acc1[3], 0, 0, 0);
        }

        // ---- epilogue1: + b + x, relu, BN -> aBuf (bf16 swizzled) ----
        const int base = t * 64;
#pragma unroll
        for (int m = 0; m < 4; m++) {
#pragma unroll
            for (int i = 0; i < 4; i++) {
                int r = m * 16 + kq * 4 + i;
                if (base + r < Nn) {
                    unsigned int sw = ((unsigned)(r & 15)) << 4;
                    float xv = bf2f(*(const unsigned short*)(X + (unsigned)r * 256u + (((unsigned)(f * 2)) ^ sw)));
                    float v = acc1[m][i] + bb + xv;
                    v = fmaxf(v, 0.f) * sc + sh;
                    *(unsigned short*)(A + (unsigned)r * 256u + (((unsigned)(f * 2)) ^ sw)) = f2bf(v);
                }
            }
        }
        asm volatile("s_waitcnt lgkmcnt(0)" ::: "memory");
        __builtin_amdgcn_sched_barrier(0);
        __builtin_amdgcn_s_barrier();

        // ---- GEMM2 in two row-halves (m pair per half) to cap live registers ----
#pragma unroll
        for (int half = 0; half < 2; half++) {
            f32x4 az[2], ar[2], axh[2], arh[2];
#pragma unroll
            for (int mm = 0; mm < 2; mm++) {
                az[mm] = (f32x4){0.f, 0.f, 0.f, 0.f};
                ar[mm] = (f32x4){0.f, 0.f, 0.f, 0.f};
                axh[mm] = (f32x4){0.f, 0.f, 0.f, 0.f};
                arh[mm] = (f32x4){0.f, 0.f, 0.f, 0.f};
            }
#pragma unroll
            for (int kk = 0; kk < 8; kk++) {
                bf16x8 a2f[2];
#pragma unroll
                for (int mm = 0; mm < 2; mm++) {
                    int m = half * 2 + mm;
                    if (kk < 4)
                        a2f[mm] = *(const bf16x8*)(A + (unsigned)(m * 16 + col0) * 256u +
                                                   (((unsigned)(kk * 64 + kq * 16)) ^ rs));
                    else
                        a2f[mm] = *(const bf16x8*)(X + (unsigned)(m * 16 + col0) * 256u +
                                                   (((unsigned)((kk - 4) * 64 + kq * 16)) ^ rs));
                }
#pragma unroll
                for (int mm = 0; mm < 2; mm++) {
                    az[mm] = __builtin_amdgcn_mfma_f32_16x16x32_bf16(a2f[mm], b2z[kk], az[mm], 0, 0, 0);
                    ar[mm] = __builtin_amdgcn_mfma_f32_16x16x32_bf16(a2f[mm], b2r[kk], ar[mm], 0, 0, 0);
                    if (kk < 4)
                        axh[mm] = __builtin_amdgcn_mfma_f32_16x16x32_bf16(a2f[mm], b2xh[kk], axh[mm], 0, 0, 0);
                    else
                        arh[mm] = __builtin_amdgcn_mfma_f32_16x16x32_bf16(a2f[mm], b2rh[kk - 4], arh[mm], 0, 0, 0);
                }
            }

            // ---- GRU epilogue for this half ----
#pragma unroll
            for (int mm = 0; mm < 2; mm++) {
                int m = half * 2 + mm;
#pragma unroll
                for (int i = 0; i < 4; i++) {
                    int r = m * 16 + kq * 4 + i;
                    int grow = base + r;
                    if (grow < Nn) {
                        float zs = az[mm][i] + cz;
                        float rsum = ar[mm][i] + cr;
                        float xh = axh[mm][i] + cxh;
                        float rh = arh[mm][i] + crh;
                        float z = 1.f / (1.f + __expf(-zs));
                        float rr = 1.f / (1.f + __expf(-rsum));
                        float u = xh + rr * rh;
                        float au = fabsf(u);
                        float tt = __expf(2.f * au);
                        float th = 1.f - 2.f / (tt + 1.f);
                        float hh = (u >= 0.f) ? th : -th;
                        unsigned int sw = ((unsigned)(r & 15)) << 4;
                        float xv = bf2f(*(const unsigned short*)(X + (unsigned)r * 256u + (((unsigned)(f * 2)) ^ sw)));
                        out[(size_t)grow * FDIM + f] = z * xv + (1.f - z) * hh;
                    }
                }
            }
        }

        // drain this iter's stage loads (6) — the 16 newer out-stores stay in flight;
        // also drain all LDS ops before buffers are reused next iter
        asm volatile("s_waitcnt vmcnt(16) lgkmcnt(0)" ::: "memory");
        __builtin_amdgcn_sched_barrier(0);
        __builtin_amdgcn_s_barrier();
        p ^= 1;
    }
#undef STAGE
}

extern "C" void kernel_launch(void* const* d_in, const int* in_sizes, int n_in,
                              void* d_out, int out_size, void* d_ws, size_t ws_size,
                              hipStream_t stream)
{
    const float* x      = (const float*)d_in[0];
    const int*   pprev  = (const int*)d_in[1];
    const int*   pnext  = (const int*)d_in[2];
    const float* wNext  = (const float*)d_in[3];
    const float* wPrev  = (const float*)d_in[4];
    const float* b      = (const float*)d_in[5];
    const float* gk     = (const float*)d_in[6];
    const float* gr     = (const float*)d_in[7];
    const float* gb     = (const float*)d_in[8];
    const float* gamma  = (const float*)d_in[9];
    const float* beta   = (const float*)d_in[10];
    const float* mean   = (const float*)d_in[11];
    const float* var    = (const float*)d_in[12];
    float* out = (float*)d_out;
    const int Nn = in_sizes[0] / FDIM;

    // ws layout: s_ws (N*512B) | xbf (N*256B) | bt1 (64KB) | bt2 (256KB) | bias2 | bnscale | bnshift
    unsigned char* ws = (unsigned char*)d_ws;
    unsigned short* s_ws = (unsigned short*)(ws + 0);
    size_t off_x  = (size_t)Nn * 512u;
    size_t off_bt = off_x + (size_t)Nn * 256u;
    unsigned short* xbf   = (unsigned short*)(ws + off_x);
    unsigned short* bt1   = (unsigned short*)(ws + off_bt);
    unsigned short* bt2   = (unsigned short*)(ws + off_bt + 65536);
    float* bias2          = (float*)(ws + off_bt + 327680);
    float* bnscale        = (float*)(ws + off_bt + 327680 + 2048);
    float* bnshift        = (float*)(ws + off_bt + 327680 + 2048 + 512);

    prep_kernel<<<643, 256, 0, stream>>>(wNext, wPrev, gk, gr, gb, gamma, beta, mean, var,
                                         bt1, bt2, bias2, bnscale, bnshift);
    x_convert<<<2048, 256, 0, stream>>>(x, xbf, Nn);
    g_gather<<<2048, 256, 0, stream>>>(xbf, pprev, pnext, s_ws, Nn);
    m_fused<<<256, 512, 0, stream>>>(s_ws, xbf, bt1, bt2, b, bnscale, bnshift, bias2, out, Nn);
}

// Round 6
// 494.940 us; speedup vs baseline: 1.8313x; 1.3555x over previous
//
#include <hip/hip_runtime.h>
#include <hip/hip_bf16.h>
#include <stdint.h>

#define FDIM 128
#define AS1 __attribute__((address_space(1)))
#define AS3 __attribute__((address_space(3)))

typedef short bf16x8 __attribute__((ext_vector_type(8)));
typedef float f32x4 __attribute__((ext_vector_type(4)));

__device__ __forceinline__ unsigned short f2bf(float f) {
    union { float f; unsigned int u; } v; v.f = f;
    unsigned int r = v.u + 0x7FFFu + ((v.u >> 16) & 1u);
    return (unsigned short)(r >> 16);
}
__device__ __forceinline__ unsigned int pack2bf(float a, float b) {
    return (unsigned int)f2bf(a) | ((unsigned int)f2bf(b) << 16);
}
__device__ __forceinline__ float bflo(unsigned int u) {
    union { unsigned int u; float f; } v; v.u = u << 16; return v.f;
}
__device__ __forceinline__ float bfhi(unsigned int u) {
    union { unsigned int u; float f; } v; v.u = u & 0xFFFF0000u; return v.f;
}
__device__ __forceinline__ float bf2f(unsigned short u) {
    union { unsigned int u; float f; } v; v.u = (unsigned int)u << 16; return v.f;
}
__device__ __forceinline__ unsigned int addpk(unsigned int a, unsigned int b) {
    float lo = bflo(a) + bflo(b);
    float hi = bfhi(a) + bfhi(b);
    unsigned int d;
    asm("v_cvt_pk_bf16_f32 %0, %1, %2" : "=v"(d) : "v"(lo), "v"(hi));
    return d;
}

// ---------------- prep: pre-swizzled bf16 B-matrices ----------------
__global__ void prep_kernel(const float* __restrict__ wNext, const float* __restrict__ wPrev,
                            const float* __restrict__ gk, const float* __restrict__ gr,
                            const float* __restrict__ gb, const float* __restrict__ gamma,
                            const float* __restrict__ beta, const float* __restrict__ mean,
                            const float* __restrict__ var,
                            unsigned short* __restrict__ bt1, unsigned short* __restrict__ bt2,
                            float* __restrict__ bias2, float* __restrict__ bnscale,
                            float* __restrict__ bnshift)
{
    int t = blockIdx.x * blockDim.x + threadIdx.x;
    if (t < 32768) {
        int n = t >> 8, k = t & 255;
        float v = (k < 128) ? wNext[k * 128 + n] : wPrev[(k - 128) * 128 + n];
        unsigned int byte = (unsigned)n * 512u + (((unsigned)(k * 2)) ^ (((unsigned)(n & 15)) << 4));
        *(unsigned short*)((unsigned char*)bt1 + byte) = f2bf(v);
    } else if (t < 32768 + 131072) {
        int e = t - 32768;
        int n = e >> 8, k = e & 255;
        float v;
        if (n < 256)      v = (k < 128) ? gk[k * 384 + n] : gr[(k - 128) * 384 + n];
        else if (n < 384) v = (k < 128) ? gk[k * 384 + n] : 0.f;
        else              v = (k < 128) ? 0.f : gr[(k - 128) * 384 + (n - 128)];
        int g = n >> 7, fl = n & 127;
        int nn = ((fl >> 4) << 6) + (g << 4) + (fl & 15);
        unsigned int byte = (unsigned)nn * 512u + (((unsigned)(k * 2)) ^ (((unsigned)(nn & 15)) << 4));
        *(unsigned short*)((unsigned char*)bt2 + byte) = f2bf(v);
    } else if (t < 32768 + 131072 + 512) {
        int n = t - (32768 + 131072);
        float v;
        if (n < 256)      v = gb[n] + gb[384 + n];
        else if (n < 384) v = gb[n];
        else              v = gb[384 + (n - 128)];
        bias2[n] = v;
    } else if (t < 32768 + 131072 + 512 + 128) {
        int f = t - (32768 + 131072 + 512);
        float s = gamma[f] * rsqrtf(var[f] + 1e-3f);
        bnscale[f] = s;
        bnshift[f] = beta[f] - mean[f] * s;
    }
}

// ---------------- x_convert: x f32 -> pre-swizzled bf16 rows (256B/row) ----------------
__global__ __launch_bounds__(256) void x_convert(const float* __restrict__ x,
                                                 unsigned short* __restrict__ xbf, int Nn)
{
    const int total = Nn * 32;
    const float4* x4 = (const float4*)x;
    for (int t = blockIdx.x * 256 + threadIdx.x; t < total; t += gridDim.x * 256) {
        int m = t >> 5, l = t & 31;
        float4 v = x4[t];
        unsigned int lo = pack2bf(v.x, v.y), hi = pack2bf(v.z, v.w);
        unsigned int byte = (unsigned)m * 256u + (((unsigned)(l * 8)) ^ (((unsigned)(m & 15)) << 4));
        uint2 pk; pk.x = lo; pk.y = hi;
        *(uint2*)((unsigned char*)xbf + byte) = pk;
    }
}

// ---------------- m_fused: 1 barrier/tile software pipeline + fused gather ----------------
// LDS: S 2x32K [0,64K) | X 3x16K [64K,112K) | A 2x16K [112K,144K)
__attribute__((amdgpu_waves_per_eu(2, 2)))
__global__ __launch_bounds__(512) void m_fused(
    const unsigned short* __restrict__ xbf,
    const int* __restrict__ pprev, const int* __restrict__ pnext,
    const unsigned short* __restrict__ bt1, const unsigned short* __restrict__ bt2p,
    const float* __restrict__ bvec, const float* __restrict__ bnscale,
    const float* __restrict__ bnshift, const float* __restrict__ bias2,
    float* __restrict__ out, int Nn)
{
    __shared__ __align__(16) unsigned char lds[147456];
    const int tid = threadIdx.x, wid = tid >> 6, lane = tid & 63;
    const int col0 = lane & 15, kq = lane >> 4;
    const unsigned int rs = (unsigned)col0 << 4;

    // persistent per-wave B fragments (pinned)
    const unsigned char* bt1b = (const unsigned char*)bt1;
    const unsigned char* bt2b = (const unsigned char*)bt2p;
    bf16x8 b1[8], b2z[8], b2r[8], b2xh[4], b2rh[4];
#pragma unroll
    for (int kk = 0; kk < 8; kk++) {
        b1[kk]  = *(const bf16x8*)(bt1b + (unsigned)(wid * 16 + col0) * 512u + (((unsigned)(kk * 64 + kq * 16)) ^ rs));
        b2z[kk] = *(const bf16x8*)(bt2b + (unsigned)(wid * 64 + 0 + col0) * 512u + (((unsigned)(kk * 64 + kq * 16)) ^ rs));
        b2r[kk] = *(const bf16x8*)(bt2b + (unsigned)(wid * 64 + 16 + col0) * 512u + (((unsigned)(kk * 64 + kq * 16)) ^ rs));
    }
#pragma unroll
    for (int kk = 0; kk < 4; kk++) {
        b2xh[kk] = *(const bf16x8*)(bt2b + (unsigned)(wid * 64 + 32 + col0) * 512u + (((unsigned)(kk * 64 + kq * 16)) ^ rs));
        b2rh[kk] = *(const bf16x8*)(bt2b + (unsigned)(wid * 64 + 48 + col0) * 512u + (((unsigned)((kk + 4) * 64 + kq * 16)) ^ rs));
    }
#pragma unroll
    for (int kk = 0; kk < 8; kk++) {
        asm volatile("" : "+v"(b1[kk]));
        asm volatile("" : "+v"(b2z[kk]));
        asm volatile("" : "+v"(b2r[kk]));
    }
#pragma unroll
    for (int kk = 0; kk < 4; kk++) {
        asm volatile("" : "+v"(b2xh[kk]));
        asm volatile("" : "+v"(b2rh[kk]));
    }

    const int f = wid * 16 + col0;
    const float bb = bvec[f], sc = bnscale[f], sh = bnshift[f];
    const float cz = bias2[f], cr = bias2[128 + f], cxh = bias2[256 + f], crh = bias2[384 + f];

    // gather task mapping: thread -> (node rg, dir, 64B portion pg)
    const int rg = tid >> 3;
    const int s8 = tid & 7;
    const int dirp = s8 >> 2;
    const int pg = s8 & 3;
    const int* pid = dirp ? pprev : pnext;
    const unsigned char* xb = (const unsigned char*)xbf;
    const unsigned char* xB = (const unsigned char*)xbf;

    const int G = (int)gridDim.x;
    const int tiles = (Nn + 63) >> 6;

    uint4 g0[4], g1[4];
    float xr[16];
    int4 idxA, idxB;

#define STAGE_X(tt, slot) do {                                                              \
    size_t xg_ = (size_t)(tt) * 16384u + (unsigned)(wid * 2048) + (unsigned)(lane * 16);    \
    unsigned xo_ = 65536u + (unsigned)(slot) * 16384u + (unsigned)(wid * 2048);             \
    __builtin_amdgcn_global_load_lds((const AS1 unsigned int*)(xB + xg_),                   \
                                     (AS3 unsigned int*)(lds + xo_), 16, 0, 0);             \
    __builtin_amdgcn_global_load_lds((const AS1 unsigned int*)(xB + xg_ + 1024),            \
                                     (AS3 unsigned int*)(lds + xo_ + 1024), 16, 0, 0);      \
} while (0)

#define GATHER_ISSUE(ix) do {                                                               \
    int gi0_ = (ix).y, gi1_ = (ix).w;                                                       \
    unsigned sw0_ = ((unsigned)(gi0_ & 15)) << 4, sw1_ = ((unsigned)(gi1_ & 15)) << 4;      \
    const unsigned char* r0_ = xb + (size_t)gi0_ * 256u;                                    \
    const unsigned char* r1_ = xb + (size_t)gi1_ * 256u;                                    \
    _Pragma("unroll")                                                                       \
    for (int j_ = 0; j_ < 4; j_++) {                                                        \
        unsigned off_ = (unsigned)(pg * 64 + j_ * 16);                                      \
        g0[j_] = *(const uint4*)(r0_ + (off_ ^ sw0_));                                      \
        g1[j_] = *(const uint4*)(r1_ + (off_ ^ sw1_));                                      \
    }                                                                                       \
} while (0)

#define IDX_LOAD(dst, tc) do {                                                              \
    int gn_ = (tc) * 64 + rg;                                                               \
    (dst) = (int4){0, 0, 0, 0};                                                             \
    if (gn_ < Nn) (dst) = *(const int4*)(pid + (size_t)4 * gn_);                            \
} while (0)

#define SUM_WRITE(slot) do {                                                                \
    unsigned char* Sd_ = lds + (unsigned)(slot) * 32768u + (unsigned)(rg * 512 + dirp * 256); \
    unsigned swd_ = ((unsigned)(rg & 15)) << 4;                                             \
    _Pragma("unroll")                                                                       \
    for (int j_ = 0; j_ < 4; j_++) {                                                        \
        uint4 a_ = g0[j_], b_ = g1[j_], d_;                                                 \
        d_.x = addpk(a_.x, b_.x); d_.y = addpk(a_.y, b_.y);                                 \
        d_.z = addpk(a_.z, b_.z); d_.w = addpk(a_.w, b_.w);                                 \
        *(uint4*)(Sd_ + (((unsigned)(pg * 64 + j_ * 16)) ^ swd_)) = d_;                     \
    }                                                                                       \
} while (0)

#define GEMM1_EPI1(sSlot, xSlot, aSlot) do {                                                \
    const unsigned char* S_ = lds + (unsigned)(sSlot) * 32768u;                             \
    f32x4 acc1[4];                                                                          \
    _Pragma("unroll")                                                                       \
    for (int m_ = 0; m_ < 4; m_++) acc1[m_] = (f32x4){bb, bb, bb, bb};                      \
    _Pragma("unroll")                                                                       \
    for (int kk_ = 0; kk_ < 8; kk_++) {                                                     \
        unsigned ko_ = ((unsigned)(kk_ * 64 + kq * 16)) ^ rs;                               \
        bf16x8 a0_ = *(const bf16x8*)(S_ + (unsigned)(0 * 16 + col0) * 512u + ko_);         \
        bf16x8 a1_ = *(const bf16x8*)(S_ + (unsigned)(1 * 16 + col0) * 512u + ko_);         \
        bf16x8 a2_ = *(const bf16x8*)(S_ + (unsigned)(2 * 16 + col0) * 512u + ko_);         \
        bf16x8 a3_ = *(const bf16x8*)(S_ + (unsigned)(3 * 16 + col0) * 512u + ko_);         \
        acc1[0] = __builtin_amdgcn_mfma_f32_16x16x32_bf16(a0_, b1[kk_], acc1[0], 0, 0, 0);  \
        acc1[1] = __builtin_amdgcn_mfma_f32_16x16x32_bf16(a1_, b1[kk_], acc1[1], 0, 0, 0);  \
        acc1[2] = __builtin_amdgcn_mfma_f32_16x16x32_bf16(a2_, b1[kk_], acc1[2], 0, 0, 0);  \
        acc1[3] = __builtin_amdgcn_mfma_f32_16x16x32_bf16(a3_, b1[kk_], acc1[3], 0, 0, 0);  \
    }                                                                                       \
    const unsigned char* X_ = lds + 65536u + (unsigned)(xSlot) * 16384u;                    \
    unsigned char* A_ = lds + 114688u + (unsigned)(aSlot) * 16384u;                         \
    _Pragma("unroll")                                                                       \
    for (int m_ = 0; m_ < 4; m_++) {                                                        \
        _Pragma("unroll")                                                                   \
        for (int i_ = 0; i_ < 4; i_++) {                                                    \
            int r_ = m_ * 16 + kq * 4 + i_;                                                 \
            unsigned sw_ = ((unsigned)(r_ & 15)) << 4;                                      \
            unsigned co_ = ((unsigned)(f * 2)) ^ sw_;                                       \
            float xv_ = bf2f(*(const unsigned short*)(X_ + (unsigned)r_ * 256u + co_));     \
            xr[m_ * 4 + i_] = xv_;                                                          \
            float v_ = acc1[m_][i_] + xv_;                                                  \
            v_ = fmaxf(v_, 0.f) * sc + sh;                                                  \
            *(unsigned short*)(A_ + (unsigned)r_ * 256u + co_) = f2bf(v_);                  \
        }                                                                                   \
    }                                                                                       \
} while (0)

    // -------- prologue --------
    const int t0 = blockIdx.x;
    {
        int4 ix0;
        { int gn = t0 * 64 + rg; ix0 = *(const int4*)(pid + (size_t)4 * gn); }
        STAGE_X(t0, 0);
        GATHER_ISSUE(ix0);
        IDX_LOAD(idxA, t0 + G);
        __builtin_amdgcn_sched_barrier(0);
        asm volatile("s_waitcnt vmcnt(1)" ::: "memory");
        __builtin_amdgcn_sched_barrier(0);
        SUM_WRITE(0);
        asm volatile("s_waitcnt lgkmcnt(0)" ::: "memory");
        __builtin_amdgcn_sched_barrier(0);
        __builtin_amdgcn_s_barrier();

        STAGE_X(t0 + G, 1);
        GATHER_ISSUE(idxA);
        IDX_LOAD(idxB, t0 + 2 * G);
        __builtin_amdgcn_sched_barrier(0);
        GEMM1_EPI1(0, 0, 0);   // tile t0
        asm volatile("s_waitcnt vmcnt(1)" ::: "memory");
        __builtin_amdgcn_sched_barrier(0);
        SUM_WRITE(1);
        asm volatile("s_waitcnt lgkmcnt(0)" ::: "memory");
        __builtin_amdgcn_sched_barrier(0);
        __builtin_amdgcn_s_barrier();
        idxA = idxB;
    }

    int qaR = 0, spR = 1, xi = 0;

    for (int t = t0; t < tiles; t += G) {
        const int base = t * 64;
        // ---- step 1: GEMM2(t) + GRU epilogue (A slot qaR, X slot xi) ----
        {
            const unsigned char* A_ = lds + 114688u + (unsigned)qaR * 16384u;
            const unsigned char* X_ = lds + 65536u + (unsigned)xi * 16384u;
#pragma unroll
            for (int half = 0; half < 2; half++) {
                f32x4 az[2], ar[2], axh[2], arh[2];
#pragma unroll
                for (int mm = 0; mm < 2; mm++) {
                    az[mm]  = (f32x4){cz, cz, cz, cz};
                    ar[mm]  = (f32x4){cr, cr, cr, cr};
                    axh[mm] = (f32x4){cxh, cxh, cxh, cxh};
                    arh[mm] = (f32x4){crh, crh, crh, crh};
                }
#pragma unroll
                for (int kk = 0; kk < 8; kk++) {
                    bf16x8 a2f[2];
#pragma unroll
                    for (int mm = 0; mm < 2; mm++) {
                        int m = half * 2 + mm;
                        if (kk < 4)
                            a2f[mm] = *(const bf16x8*)(A_ + (unsigned)(m * 16 + col0) * 256u +
                                                       (((unsigned)(kk * 64 + kq * 16)) ^ rs));
                        else
                            a2f[mm] = *(const bf16x8*)(X_ + (unsigned)(m * 16 + col0) * 256u +
                                                       (((unsigned)((kk - 4) * 64 + kq * 16)) ^ rs));
                    }
#pragma unroll
                    for (int mm = 0; mm < 2; mm++) {
                        az[mm] = __builtin_amdgcn_mfma_f32_16x16x32_bf16(a2f[mm], b2z[kk], az[mm], 0, 0, 0);
                        ar[mm] = __builtin_amdgcn_mfma_f32_16x16x32_bf16(a2f[mm], b2r[kk], ar[mm], 0, 0, 0);
                        if (kk < 4)
                            axh[mm] = __builtin_amdgcn_mfma_f32_16x16x32_bf16(a2f[mm], b2xh[kk], axh[mm], 0, 0, 0);
                        else
                            arh[mm] = __builtin_amdgcn_mfma_f32_16x16x32_bf16(a2f[mm], b2rh[kk - 4], arh[mm], 0, 0, 0);
                    }
                }
#pragma unroll
                for (int mm = 0; mm < 2; mm++) {
                    int m = half * 2 + mm;
#pragma unroll
                    for (int i = 0; i < 4; i++) {
                        int r = m * 16 + kq * 4 + i;
                        int grow = base + r;
                        if (grow < Nn) {
                            float z  = __builtin_amdgcn_rcpf(1.f + __expf(-az[mm][i]));
                            float rr = __builtin_amdgcn_rcpf(1.f + __expf(-ar[mm][i]));
                            float u  = axh[mm][i] + rr * arh[mm][i];
                            float th = 1.f - 2.f * __builtin_amdgcn_rcpf(__expf(2.f * u) + 1.f);
                            float xv = xr[m * 4 + i];
                            __builtin_nontemporal_store(th + z * (xv - th), out + (size_t)grow * FDIM + f);
                        }
                    }
                }
            }
        }
        // ---- step 2: issue prefetches for t+2G (clamped, branchless vmcnt count) ----
        {
            int tn2 = t + 2 * G, tn3 = t + 3 * G;
            int tc2 = (tn2 < tiles) ? tn2 : 0;
            int tc3 = (tn3 < tiles) ? tn3 : 0;
            int xs = xi + 2; if (xs >= 3) xs -= 3;
            STAGE_X(tc2, xs);
            GATHER_ISSUE(idxA);
            IDX_LOAD(idxB, tc3);
            __builtin_amdgcn_sched_barrier(0);
        }
        // ---- step 3: GEMM1 + epi1 of tile t+G (always executed; garbage-safe on tail) ----
        {
            int xn = xi + 1; if (xn >= 3) xn -= 3;
            GEMM1_EPI1(spR, xn, qaR ^ 1);
        }
        // ---- step 4: gather sum -> S(spR^1) ----
        asm volatile("s_waitcnt vmcnt(1)" ::: "memory");
        __builtin_amdgcn_sched_barrier(0);
        SUM_WRITE(spR ^ 1);
        // ---- step 5: publish ----
        asm volatile("s_waitcnt lgkmcnt(0)" ::: "memory");
        __builtin_amdgcn_sched_barrier(0);
        __builtin_amdgcn_s_barrier();
        // rotate
        idxA = idxB; qaR ^= 1; spR ^= 1; xi = (xi == 2) ? 0 : xi + 1;
    }
#undef STAGE_X
#undef GATHER_ISSUE
#undef IDX_LOAD
#undef SUM_WRITE
#undef GEMM1_EPI1
}

extern "C" void kernel_launch(void* const* d_in, const int* in_sizes, int n_in,
                              void* d_out, int out_size, void* d_ws, size_t ws_size,
                              hipStream_t stream)
{
    const float* x      = (const float*)d_in[0];
    const int*   pprev  = (const int*)d_in[1];
    const int*   pnext  = (const int*)d_in[2];
    const float* wNext  = (const float*)d_in[3];
    const float* wPrev  = (const float*)d_in[4];
    const float* b      = (const float*)d_in[5];
    const float* gk     = (const float*)d_in[6];
    const float* gr     = (const float*)d_in[7];
    const float* gb     = (const float*)d_in[8];
    const float* gamma  = (const float*)d_in[9];
    const float* beta   = (const float*)d_in[10];
    const float* mean   = (const float*)d_in[11];
    const float* var    = (const float*)d_in[12];
    float* out = (float*)d_out;
    const int Nn = in_sizes[0] / FDIM;

    // ws layout: xbf (N*256B) | bt1 (64KB) | bt2 (256KB) | bias2 | bnscale | bnshift
    unsigned char* ws = (unsigned char*)d_ws;
    unsigned short* xbf = (unsigned short*)(ws + 0);
    size_t off_bt = (size_t)Nn * 256u;
    unsigned short* bt1   = (unsigned short*)(ws + off_bt);
    unsigned short* bt2   = (unsigned short*)(ws + off_bt + 65536);
    float* bias2          = (float*)(ws + off_bt + 327680);
    float* bnscale        = (float*)(ws + off_bt + 327680 + 2048);
    float* bnshift        = (float*)(ws + off_bt + 327680 + 2048 + 512);

    prep_kernel<<<643, 256, 0, stream>>>(wNext, wPrev, gk, gr, gb, gamma, beta, mean, var,
                                         bt1, bt2, bias2, bnscale, bnshift);
    x_convert<<<2048, 256, 0, stream>>>(x, xbf, Nn);
    m_fused<<<256, 512, 0, stream>>>(xbf, pprev, pnext, bt1, bt2, b, bnscale, bnshift,
                                     bias2, out, Nn);
}

// Round 7
// 378.921 us; speedup vs baseline: 2.3920x; 1.3062x over previous
//
#include <hip/hip_runtime.h>
#include <hip/hip_bf16.h>
#include <stdint.h>

#define FDIM 128
#define AS1 __attribute__((address_space(1)))
#define AS3 __attribute__((address_space(3)))

typedef short bf16x8 __attribute__((ext_vector_type(8)));
typedef float f32x4 __attribute__((ext_vector_type(4)));

__device__ __forceinline__ unsigned short f2bf(float f) {
    union { float f; unsigned int u; } v; v.f = f;
    unsigned int r = v.u + 0x7FFFu + ((v.u >> 16) & 1u);
    return (unsigned short)(r >> 16);
}
__device__ __forceinline__ unsigned int pack2bf(float a, float b) {
    return (unsigned int)f2bf(a) | ((unsigned int)f2bf(b) << 16);
}
__device__ __forceinline__ float bflo(unsigned int u) {
    union { unsigned int u; float f; } v; v.u = u << 16; return v.f;
}
__device__ __forceinline__ float bfhi(unsigned int u) {
    union { unsigned int u; float f; } v; v.u = u & 0xFFFF0000u; return v.f;
}
__device__ __forceinline__ float bf2f(unsigned short u) {
    union { unsigned int u; float f; } v; v.u = (unsigned int)u << 16; return v.f;
}
__device__ __forceinline__ unsigned int addpk(unsigned int a, unsigned int b) {
    float lo = bflo(a) + bflo(b);
    float hi = bfhi(a) + bfhi(b);
    unsigned int d;
    asm("v_cvt_pk_bf16_f32 %0, %1, %2" : "=v"(d) : "v"(lo), "v"(hi));
    return d;
}

// ---------------- prep: pre-swizzled bf16 B-matrices ----------------
// bt1[n][k] n<128, k<256: k<128 -> wNext[k][n] else wPrev[k-128][n]
// bt2 PERMUTED rows: original row n (gate g=n>>7, feature fl=n&127) stored at
//   nn = (fl>>4)*64 + g*16 + (fl&15)   -> wave w owns rows [w*64, w*64+64)
__global__ void prep_kernel(const float* __restrict__ wNext, const float* __restrict__ wPrev,
                            const float* __restrict__ gk, const float* __restrict__ gr,
                            const float* __restrict__ gb, const float* __restrict__ gamma,
                            const float* __restrict__ beta, const float* __restrict__ mean,
                            const float* __restrict__ var,
                            unsigned short* __restrict__ bt1, unsigned short* __restrict__ bt2,
                            float* __restrict__ bias2, float* __restrict__ bnscale,
                            float* __restrict__ bnshift)
{
    int t = blockIdx.x * blockDim.x + threadIdx.x;
    if (t < 32768) {
        int n = t >> 8, k = t & 255;
        float v = (k < 128) ? wNext[k * 128 + n] : wPrev[(k - 128) * 128 + n];
        unsigned int byte = (unsigned)n * 512u + (((unsigned)(k * 2)) ^ (((unsigned)(n & 15)) << 4));
        *(unsigned short*)((unsigned char*)bt1 + byte) = f2bf(v);
    } else if (t < 32768 + 131072) {
        int e = t - 32768;
        int n = e >> 8, k = e & 255;
        float v;
        if (n < 256)      v = (k < 128) ? gk[k * 384 + n] : gr[(k - 128) * 384 + n];
        else if (n < 384) v = (k < 128) ? gk[k * 384 + n] : 0.f;
        else              v = (k < 128) ? 0.f : gr[(k - 128) * 384 + (n - 128)];
        int g = n >> 7, fl = n & 127;
        int nn = ((fl >> 4) << 6) + (g << 4) + (fl & 15);
        unsigned int byte = (unsigned)nn * 512u + (((unsigned)(k * 2)) ^ (((unsigned)(nn & 15)) << 4));
        *(unsigned short*)((unsigned char*)bt2 + byte) = f2bf(v);
    } else if (t < 32768 + 131072 + 512) {
        int n = t - (32768 + 131072);
        float v;
        if (n < 256)      v = gb[n] + gb[384 + n];
        else if (n < 384) v = gb[n];
        else              v = gb[384 + (n - 128)];
        bias2[n] = v;
    } else if (t < 32768 + 131072 + 512 + 128) {
        int f = t - (32768 + 131072 + 512);
        float s = gamma[f] * rsqrtf(var[f] + 1e-3f);
        bnscale[f] = s;
        bnshift[f] = beta[f] - mean[f] * s;
    }
}

// ---------------- x_convert: x f32 -> pre-swizzled bf16 rows (256B/row) ----------------
__global__ __launch_bounds__(256) void x_convert(const float* __restrict__ x,
                                                 unsigned short* __restrict__ xbf, int Nn)
{
    const int total = Nn * 32;
    const float4* x4 = (const float4*)x;
    for (int t = blockIdx.x * 256 + threadIdx.x; t < total; t += gridDim.x * 256) {
        int m = t >> 5, l = t & 31;
        float4 v = x4[t];
        unsigned int lo = pack2bf(v.x, v.y), hi = pack2bf(v.z, v.w);
        unsigned int byte = (unsigned)m * 256u + (((unsigned)(l * 8)) ^ (((unsigned)(m & 15)) << 4));
        uint2 pk; pk.x = lo; pk.y = hi;
        *(uint2*)((unsigned char*)xbf + byte) = pk;
    }
}

// ---------------- kA: gather + sum + GEMM1 + BN -> a_ws (bf16, pre-swizzled) ----------------
// LDS: S 32K [0,32K) | X 16K [32K,48K). Target 4 waves/SIMD (2 blocks/CU).
__attribute__((amdgpu_waves_per_eu(4, 8)))
__global__ __launch_bounds__(512) void k_gather_g1(
    const unsigned short* __restrict__ xbf,
    const int* __restrict__ pprev, const int* __restrict__ pnext,
    const unsigned short* __restrict__ bt1,
    const float* __restrict__ bvec, const float* __restrict__ bnscale,
    const float* __restrict__ bnshift,
    unsigned short* __restrict__ a_out, int Nn)
{
    __shared__ __align__(16) unsigned char lds[49152];
    const int tid = threadIdx.x, wid = tid >> 6, lane = tid & 63;
    const int col0 = lane & 15, kq = lane >> 4;
    const unsigned int rs = (unsigned)col0 << 4;

    // b1: 32 regs, pinned
    const unsigned char* bt1b = (const unsigned char*)bt1;
    bf16x8 b1[8];
#pragma unroll
    for (int kk = 0; kk < 8; kk++)
        b1[kk] = *(const bf16x8*)(bt1b + (unsigned)(wid * 16 + col0) * 512u +
                                  (((unsigned)(kk * 64 + kq * 16)) ^ rs));
#pragma unroll
    for (int kk = 0; kk < 8; kk++) asm volatile("" : "+v"(b1[kk]));

    const int f = wid * 16 + col0;
    const float bb = bvec[f], sc = bnscale[f], sh = bnshift[f];

    const int rg = tid >> 3, s8 = tid & 7, dirp = s8 >> 2, pg = s8 & 3;
    const int* pid = dirp ? pprev : pnext;
    const unsigned char* xb = (const unsigned char*)xbf;

    const int G = (int)gridDim.x;
    const int tiles = (Nn + 63) >> 6;

    uint4 g0[4], g1[4];
    int4 idxA = {0, 0, 0, 0}, idxB;
    { int gn = blockIdx.x * 64 + rg; if (gn < Nn) idxA = *(const int4*)(pid + (size_t)4 * gn); }

    for (int t = blockIdx.x; t < tiles; t += G) {
        const int base = t * 64;
        // stage X tile (16KB, linear from pre-swizzled xbf)
        {
            size_t xg = (size_t)base * 256u + (unsigned)(wid * 2048) + (unsigned)(lane * 16);
            __builtin_amdgcn_global_load_lds((const AS1 unsigned int*)(xb + xg),
                (AS3 unsigned int*)(lds + 32768u + (unsigned)(wid * 2048)), 16, 0, 0);
            __builtin_amdgcn_global_load_lds((const AS1 unsigned int*)(xb + xg + 1024),
                (AS3 unsigned int*)(lds + 32768u + (unsigned)(wid * 2048) + 1024u), 16, 0, 0);
        }
        // gather both neighbors (8 x 16B)
        {
            int gi0 = idxA.y, gi1 = idxA.w;
            unsigned sw0 = ((unsigned)(gi0 & 15)) << 4, sw1 = ((unsigned)(gi1 & 15)) << 4;
            const unsigned char* r0 = xb + (size_t)gi0 * 256u;
            const unsigned char* r1 = xb + (size_t)gi1 * 256u;
#pragma unroll
            for (int j = 0; j < 4; j++) {
                unsigned off = (unsigned)(pg * 64 + j * 16);
                g0[j] = *(const uint4*)(r0 + (off ^ sw0));
                g1[j] = *(const uint4*)(r1 + (off ^ sw1));
            }
        }
        __builtin_amdgcn_sched_barrier(0);
        // prefetch next tile's indices (issued after gathers; stays outstanding across vmcnt(1))
        idxB = (int4){0, 0, 0, 0};
        {
            int gn = (t + G) * 64 + rg;
            if (t + G < tiles && gn < Nn) idxB = *(const int4*)(pid + (size_t)4 * gn);
        }
        __builtin_amdgcn_sched_barrier(0);
        asm volatile("s_waitcnt vmcnt(1)" ::: "memory");
        __builtin_amdgcn_sched_barrier(0);
        // sum -> S
        {
            unsigned char* Sd = lds + (unsigned)(rg * 512 + dirp * 256);
            unsigned swd = ((unsigned)(rg & 15)) << 4;
#pragma unroll
            for (int j = 0; j < 4; j++) {
                uint4 a = g0[j], b = g1[j], d;
                d.x = addpk(a.x, b.x); d.y = addpk(a.y, b.y);
                d.z = addpk(a.z, b.z); d.w = addpk(a.w, b.w);
                *(uint4*)(Sd + (((unsigned)(pg * 64 + j * 16)) ^ swd)) = d;
            }
        }
        asm volatile("s_waitcnt lgkmcnt(0)" ::: "memory");
        __builtin_amdgcn_sched_barrier(0);
        __builtin_amdgcn_s_barrier();

        // GEMM1: 64 rows x wave's 16 cols
        f32x4 acc1[4];
#pragma unroll
        for (int m = 0; m < 4; m++) acc1[m] = (f32x4){bb, bb, bb, bb};
#pragma unroll
        for (int kk = 0; kk < 8; kk++) {
            unsigned ko = ((unsigned)(kk * 64 + kq * 16)) ^ rs;
            bf16x8 a0 = *(const bf16x8*)(lds + (unsigned)(0 * 16 + col0) * 512u + ko);
            bf16x8 a1 = *(const bf16x8*)(lds + (unsigned)(1 * 16 + col0) * 512u + ko);
            bf16x8 a2 = *(const bf16x8*)(lds + (unsigned)(2 * 16 + col0) * 512u + ko);
            bf16x8 a3 = *(const bf16x8*)(lds + (unsigned)(3 * 16 + col0) * 512u + ko);
            acc1[0] = __builtin_amdgcn_mfma_f32_16x16x32_bf16(a0, b1[kk], acc1[0], 0, 0, 0);
            acc1[1] = __builtin_amdgcn_mfma_f32_16x16x32_bf16(a1, b1[kk], acc1[1], 0, 0, 0);
            acc1[2] = __builtin_amdgcn_mfma_f32_16x16x32_bf16(a2, b1[kk], acc1[2], 0, 0, 0);
            acc1[3] = __builtin_amdgcn_mfma_f32_16x16x32_bf16(a3, b1[kk], acc1[3], 0, 0, 0);
        }
        // epi1: + x, relu, BN -> a_out (bf16 swizzled rows, nontemporal)
        {
            const unsigned char* X = lds + 32768u;
#pragma unroll
            for (int m = 0; m < 4; m++) {
#pragma unroll
                for (int i = 0; i < 4; i++) {
                    int r = m * 16 + kq * 4 + i;
                    int grow = base + r;
                    if (grow < Nn) {
                        unsigned sw = ((unsigned)(r & 15)) << 4;
                        unsigned co = ((unsigned)(f * 2)) ^ sw;
                        float xv = bf2f(*(const unsigned short*)(X + (unsigned)r * 256u + co));
                        float v = acc1[m][i] + xv;
                        v = fmaxf(v, 0.f) * sc + sh;
                        __builtin_nontemporal_store(
                            f2bf(v),
                            (unsigned short*)((unsigned char*)a_out + (size_t)grow * 256u + co));
                    }
                }
            }
        }
        __builtin_amdgcn_s_barrier();   // S/X reuse safety
        idxA = idxB;
    }
}

// ---------------- kB: [a|x] @ B2 (sparse, in regs) + GRU -> out, streaming dbuf ----------------
// LDS: buf p at p*32768: A 16K + X 16K
__attribute__((amdgpu_waves_per_eu(2, 2)))
__global__ __launch_bounds__(512) void k_g2_gru(
    const unsigned short* __restrict__ a_in, const unsigned short* __restrict__ xbf,
    const unsigned short* __restrict__ bt2p, const float* __restrict__ bias2,
    float* __restrict__ out, int Nn)
{
    __shared__ __align__(16) unsigned char lds[65536];
    const int tid = threadIdx.x, wid = tid >> 6, lane = tid & 63;
    const int col0 = lane & 15, kq = lane >> 4;
    const unsigned int rs = (unsigned)col0 << 4;

    // B2 sparse fragments: 96 regs, pinned
    const unsigned char* bt2b = (const unsigned char*)bt2p;
    bf16x8 b2z[8], b2r[8], b2xh[4], b2rh[4];
#pragma unroll
    for (int kk = 0; kk < 8; kk++) {
        b2z[kk] = *(const bf16x8*)(bt2b + (unsigned)(wid * 64 + 0 + col0) * 512u + (((unsigned)(kk * 64 + kq * 16)) ^ rs));
        b2r[kk] = *(const bf16x8*)(bt2b + (unsigned)(wid * 64 + 16 + col0) * 512u + (((unsigned)(kk * 64 + kq * 16)) ^ rs));
    }
#pragma unroll
    for (int kk = 0; kk < 4; kk++) {
        b2xh[kk] = *(const bf16x8*)(bt2b + (unsigned)(wid * 64 + 32 + col0) * 512u + (((unsigned)(kk * 64 + kq * 16)) ^ rs));
        b2rh[kk] = *(const bf16x8*)(bt2b + (unsigned)(wid * 64 + 48 + col0) * 512u + (((unsigned)((kk + 4) * 64 + kq * 16)) ^ rs));
    }
#pragma unroll
    for (int kk = 0; kk < 8; kk++) {
        asm volatile("" : "+v"(b2z[kk]));
        asm volatile("" : "+v"(b2r[kk]));
    }
#pragma unroll
    for (int kk = 0; kk < 4; kk++) {
        asm volatile("" : "+v"(b2xh[kk]));
        asm volatile("" : "+v"(b2rh[kk]));
    }

    const int f = wid * 16 + col0;
    const float cz = bias2[f], cr = bias2[128 + f], cxh = bias2[256 + f], crh = bias2[384 + f];

    const unsigned char* aB = (const unsigned char*)a_in;
    const unsigned char* xB = (const unsigned char*)xbf;
    const int G = (int)gridDim.x;
    const int tiles = (Nn + 63) >> 6;

#define STAGE2(tt, pp) do {                                                                  \
    size_t g_ = (size_t)(tt) * 16384u + (unsigned)(wid * 2048) + (unsigned)(lane * 16);      \
    unsigned o_ = (unsigned)(pp) * 32768u + (unsigned)(wid * 2048);                          \
    __builtin_amdgcn_global_load_lds((const AS1 unsigned int*)(aB + g_),                     \
                                     (AS3 unsigned int*)(lds + o_), 16, 0, 0);               \
    __builtin_amdgcn_global_load_lds((const AS1 unsigned int*)(aB + g_ + 1024),              \
                                     (AS3 unsigned int*)(lds + o_ + 1024), 16, 0, 0);        \
    __builtin_amdgcn_global_load_lds((const AS1 unsigned int*)(xB + g_),                     \
                                     (AS3 unsigned int*)(lds + o_ + 16384u), 16, 0, 0);      \
    __builtin_amdgcn_global_load_lds((const AS1 unsigned int*)(xB + g_ + 1024),              \
                                     (AS3 unsigned int*)(lds + o_ + 16384u + 1024), 16, 0, 0);\
} while (0)

    // prologue
    STAGE2(blockIdx.x, 0);
    asm volatile("s_waitcnt vmcnt(0)" ::: "memory");
    __builtin_amdgcn_sched_barrier(0);
    __builtin_amdgcn_s_barrier();

    int p = 0;
    for (int t = blockIdx.x; t < tiles; t += G) {
        const int base = t * 64;
        // prefetch next tile (clamped -> constant vmem count)
        {
            int tn = t + G;
            int tc = (tn < tiles) ? tn : t;
            STAGE2(tc, p ^ 1);
        }
        const unsigned char* A_ = lds + (unsigned)p * 32768u;
        const unsigned char* X_ = lds + (unsigned)p * 32768u + 16384u;

#pragma unroll
        for (int half = 0; half < 2; half++) {
            f32x4 az[2], ar[2], axh[2], arh[2];
#pragma unroll
            for (int mm = 0; mm < 2; mm++) {
                az[mm]  = (f32x4){cz, cz, cz, cz};
                ar[mm]  = (f32x4){cr, cr, cr, cr};
                axh[mm] = (f32x4){cxh, cxh, cxh, cxh};
                arh[mm] = (f32x4){crh, crh, crh, crh};
            }
#pragma unroll
            for (int kk = 0; kk < 8; kk++) {
                bf16x8 a2f[2];
#pragma unroll
                for (int mm = 0; mm < 2; mm++) {
                    int m = half * 2 + mm;
                    if (kk < 4)
                        a2f[mm] = *(const bf16x8*)(A_ + (unsigned)(m * 16 + col0) * 256u +
                                                   (((unsigned)(kk * 64 + kq * 16)) ^ rs));
                    else
                        a2f[mm] = *(const bf16x8*)(X_ + (unsigned)(m * 16 + col0) * 256u +
                                                   (((unsigned)((kk - 4) * 64 + kq * 16)) ^ rs));
                }
#pragma unroll
                for (int mm = 0; mm < 2; mm++) {
                    az[mm] = __builtin_amdgcn_mfma_f32_16x16x32_bf16(a2f[mm], b2z[kk], az[mm], 0, 0, 0);
                    ar[mm] = __builtin_amdgcn_mfma_f32_16x16x32_bf16(a2f[mm], b2r[kk], ar[mm], 0, 0, 0);
                    if (kk < 4)
                        axh[mm] = __builtin_amdgcn_mfma_f32_16x16x32_bf16(a2f[mm], b2xh[kk], axh[mm], 0, 0, 0);
                    else
                        arh[mm] = __builtin_amdgcn_mfma_f32_16x16x32_bf16(a2f[mm], b2rh[kk - 4], arh[mm], 0, 0, 0);
                }
            }
            // GRU epilogue for this half
#pragma unroll
            for (int mm = 0; mm < 2; mm++) {
                int m = half * 2 + mm;
#pragma unroll
                for (int i = 0; i < 4; i++) {
                    int r = m * 16 + kq * 4 + i;
                    int grow = base + r;
                    if (grow < Nn) {
                        float z  = __builtin_amdgcn_rcpf(1.f + __expf(-az[mm][i]));
                        float rr = __builtin_amdgcn_rcpf(1.f + __expf(-ar[mm][i]));
                        float u  = axh[mm][i] + rr * arh[mm][i];
                        float th = 1.f - 2.f * __builtin_amdgcn_rcpf(__expf(2.f * u) + 1.f);
                        unsigned sw = ((unsigned)(r & 15)) << 4;
                        float xv = bf2f(*(const unsigned short*)(X_ + (unsigned)r * 256u +
                                                                 (((unsigned)(f * 2)) ^ sw)));
                        __builtin_nontemporal_store(th + z * (xv - th),
                                                    out + (size_t)grow * FDIM + f);
                    }
                }
            }
        }
        // drain this iter's 4 stage loads (16 newer out-stores stay in flight)
        asm volatile("s_waitcnt vmcnt(16) lgkmcnt(0)" ::: "memory");
        __builtin_amdgcn_sched_barrier(0);
        __builtin_amdgcn_s_barrier();
        p ^= 1;
    }
#undef STAGE2
}

extern "C" void kernel_launch(void* const* d_in, const int* in_sizes, int n_in,
                              void* d_out, int out_size, void* d_ws, size_t ws_size,
                              hipStream_t stream)
{
    const float* x      = (const float*)d_in[0];
    const int*   pprev  = (const int*)d_in[1];
    const int*   pnext  = (const int*)d_in[2];
    const float* wNext  = (const float*)d_in[3];
    const float* wPrev  = (const float*)d_in[4];
    const float* b      = (const float*)d_in[5];
    const float* gk     = (const float*)d_in[6];
    const float* gr     = (const float*)d_in[7];
    const float* gb     = (const float*)d_in[8];
    const float* gamma  = (const float*)d_in[9];
    const float* beta   = (const float*)d_in[10];
    const float* mean   = (const float*)d_in[11];
    const float* var    = (const float*)d_in[12];
    float* out = (float*)d_out;
    const int Nn = in_sizes[0] / FDIM;

    // ws: xbf (N*256B) | a_ws (N*256B) | bt1 (64KB) | bt2 (256KB) | bias2 | bnscale | bnshift
    unsigned char* ws = (unsigned char*)d_ws;
    unsigned short* xbf  = (unsigned short*)(ws + 0);
    unsigned short* a_ws = (unsigned short*)(ws + (size_t)Nn * 256u);
    size_t off_bt = (size_t)Nn * 512u;
    unsigned short* bt1   = (unsigned short*)(ws + off_bt);
    unsigned short* bt2   = (unsigned short*)(ws + off_bt + 65536);
    float* bias2          = (float*)(ws + off_bt + 327680);
    float* bnscale        = (float*)(ws + off_bt + 327680 + 2048);
    float* bnshift        = (float*)(ws + off_bt + 327680 + 2048 + 512);

    prep_kernel<<<643, 256, 0, stream>>>(wNext, wPrev, gk, gr, gb, gamma, beta, mean, var,
                                         bt1, bt2, bias2, bnscale, bnshift);
    x_convert<<<2048, 256, 0, stream>>>(x, xbf, Nn);
    k_gather_g1<<<512, 512, 0, stream>>>(xbf, pprev, pnext, bt1, b, bnscale, bnshift, a_ws, Nn);
    k_g2_gru<<<256, 512, 0, stream>>>(a_ws, xbf, bt2, bias2, out, Nn);
}

// Round 8
// 329.267 us; speedup vs baseline: 2.7527x; 1.1508x over previous
//
#include <hip/hip_runtime.h>
#include <hip/hip_bf16.h>
#include <stdint.h>

#define FDIM 128
#define AS1 __attribute__((address_space(1)))
#define AS3 __attribute__((address_space(3)))

typedef short bf16x8 __attribute__((ext_vector_type(8)));
typedef float f32x4 __attribute__((ext_vector_type(4)));
typedef float f32x2 __attribute__((ext_vector_type(2)));

__device__ __forceinline__ unsigned short f2bf(float f) {
    union { float f; unsigned int u; } v; v.f = f;
    unsigned int r = v.u + 0x7FFFu + ((v.u >> 16) & 1u);
    return (unsigned short)(r >> 16);
}
__device__ __forceinline__ unsigned int pack2bf(float a, float b) {
    return (unsigned int)f2bf(a) | ((unsigned int)f2bf(b) << 16);
}
__device__ __forceinline__ float bf2f(unsigned short u) {
    union { unsigned int u; float f; } v; v.u = (unsigned int)u << 16; return v.f;
}
// dequant 4 fp8 (w0: row0) + 4 fp8 (w1: row1), sum pairwise -> 4 bf16 (uint2)
__device__ __forceinline__ uint2 sum4fp8(unsigned int w0, unsigned int w1) {
    f32x2 a0 = __builtin_amdgcn_cvt_pk_f32_fp8((int)w0, false);
    f32x2 a1 = __builtin_amdgcn_cvt_pk_f32_fp8((int)w0, true);
    f32x2 b0 = __builtin_amdgcn_cvt_pk_f32_fp8((int)w1, false);
    f32x2 b1 = __builtin_amdgcn_cvt_pk_f32_fp8((int)w1, true);
    float s0 = a0.x + b0.x, s1 = a0.y + b0.y;
    float s2 = a1.x + b1.x, s3 = a1.y + b1.y;
    uint2 r;
    asm("v_cvt_pk_bf16_f32 %0, %1, %2" : "=v"(r.x) : "v"(s0), "v"(s1));
    asm("v_cvt_pk_bf16_f32 %0, %1, %2" : "=v"(r.y) : "v"(s2), "v"(s3));
    return r;
}

// ---------------- prep: pre-swizzled bf16 B-matrices ----------------
// bt1[n][k] n<128, k<256: k<128 -> wNext[k][n] else wPrev[k-128][n]
// bt2 PERMUTED rows: row n (gate g=n>>7, feat fl=n&127) at nn=(fl>>4)*64+g*16+(fl&15)
__global__ void prep_kernel(const float* __restrict__ wNext, const float* __restrict__ wPrev,
                            const float* __restrict__ gk, const float* __restrict__ gr,
                            const float* __restrict__ gb, const float* __restrict__ gamma,
                            const float* __restrict__ beta, const float* __restrict__ mean,
                            const float* __restrict__ var,
                            unsigned short* __restrict__ bt1, unsigned short* __restrict__ bt2,
                            float* __restrict__ bias2, float* __restrict__ bnscale,
                            float* __restrict__ bnshift)
{
    int t = blockIdx.x * blockDim.x + threadIdx.x;
    if (t < 32768) {
        int n = t >> 8, k = t & 255;
        float v = (k < 128) ? wNext[k * 128 + n] : wPrev[(k - 128) * 128 + n];
        unsigned int byte = (unsigned)n * 512u + (((unsigned)(k * 2)) ^ (((unsigned)(n & 15)) << 4));
        *(unsigned short*)((unsigned char*)bt1 + byte) = f2bf(v);
    } else if (t < 32768 + 131072) {
        int e = t - 32768;
        int n = e >> 8, k = e & 255;
        float v;
        if (n < 256)      v = (k < 128) ? gk[k * 384 + n] : gr[(k - 128) * 384 + n];
        else if (n < 384) v = (k < 128) ? gk[k * 384 + n] : 0.f;
        else              v = (k < 128) ? 0.f : gr[(k - 128) * 384 + (n - 128)];
        int g = n >> 7, fl = n & 127;
        int nn = ((fl >> 4) << 6) + (g << 4) + (fl & 15);
        unsigned int byte = (unsigned)nn * 512u + (((unsigned)(k * 2)) ^ (((unsigned)(nn & 15)) << 4));
        *(unsigned short*)((unsigned char*)bt2 + byte) = f2bf(v);
    } else if (t < 32768 + 131072 + 512) {
        int n = t - (32768 + 131072);
        float v;
        if (n < 256)      v = gb[n] + gb[384 + n];
        else if (n < 384) v = gb[n];
        else              v = gb[384 + (n - 128)];
        bias2[n] = v;
    } else if (t < 32768 + 131072 + 512 + 128) {
        int f = t - (32768 + 131072 + 512);
        float s = gamma[f] * rsqrtf(var[f] + 1e-3f);
        bnscale[f] = s;
        bnshift[f] = beta[f] - mean[f] * s;
    }
}

// ---------------- x_convert: x f32 -> xbf (bf16 swizzled 256B rows) + xq (fp8 linear 128B rows)
__global__ __launch_bounds__(256) void x_convert(const float* __restrict__ x,
                                                 unsigned short* __restrict__ xbf,
                                                 unsigned char* __restrict__ xq, int Nn)
{
    const int total = Nn * 16;   // one thread per 8 columns
    const float4* x4 = (const float4*)x;
    for (int t = blockIdx.x * 256 + threadIdx.x; t < total; t += gridDim.x * 256) {
        int m = t >> 4, l = t & 15;
        float4 v0 = x4[m * 32 + l * 2];
        float4 v1 = x4[m * 32 + l * 2 + 1];
        uint4 pk;
        pk.x = pack2bf(v0.x, v0.y); pk.y = pack2bf(v0.z, v0.w);
        pk.z = pack2bf(v1.x, v1.y); pk.w = pack2bf(v1.z, v1.w);
        unsigned int byte = (unsigned)m * 256u + (((unsigned)(l * 16)) ^ (((unsigned)(m & 15)) << 4));
        *(uint4*)((unsigned char*)xbf + byte) = pk;
        int q0 = __builtin_amdgcn_cvt_pk_fp8_f32(v0.x, v0.y, 0, false);
        q0 = __builtin_amdgcn_cvt_pk_fp8_f32(v0.z, v0.w, q0, true);
        int q1 = __builtin_amdgcn_cvt_pk_fp8_f32(v1.x, v1.y, 0, false);
        q1 = __builtin_amdgcn_cvt_pk_fp8_f32(v1.z, v1.w, q1, true);
        uint2 qq; qq.x = (unsigned)q0; qq.y = (unsigned)q1;
        *(uint2*)(xq + (size_t)m * 128u + (unsigned)(l * 8)) = qq;
    }
}

// ---------------- kA: fp8 gather + sum + GEMM1 + BN -> a_ws (bf16, pre-swizzled) ----------------
// LDS: S 32K [0,32K) | X 16K [32K,48K). 3 blocks/CU (grid 768).
__attribute__((amdgpu_waves_per_eu(4, 8)))
__global__ __launch_bounds__(512) void k_gather_g1(
    const unsigned short* __restrict__ xbf, const unsigned char* __restrict__ xq,
    const int* __restrict__ pprev, const int* __restrict__ pnext,
    const unsigned short* __restrict__ bt1,
    const float* __restrict__ bvec, const float* __restrict__ bnscale,
    const float* __restrict__ bnshift,
    unsigned short* __restrict__ a_out, int Nn)
{
    __shared__ __align__(16) unsigned char lds[49152];
    const int tid = threadIdx.x, wid = tid >> 6, lane = tid & 63;
    const int col0 = lane & 15, kq = lane >> 4;
    const unsigned int rs = (unsigned)col0 << 4;

    // b1: 32 regs, pinned
    const unsigned char* bt1b = (const unsigned char*)bt1;
    bf16x8 b1[8];
#pragma unroll
    for (int kk = 0; kk < 8; kk++)
        b1[kk] = *(const bf16x8*)(bt1b + (unsigned)(wid * 16 + col0) * 512u +
                                  (((unsigned)(kk * 64 + kq * 16)) ^ rs));
#pragma unroll
    for (int kk = 0; kk < 8; kk++) asm volatile("" : "+v"(b1[kk]));

    const int f = wid * 16 + col0;
    const float bb = bvec[f], sc = bnscale[f], sh = bnshift[f];

    const int rg = tid >> 3, s8 = tid & 7, dirp = s8 >> 2, pg = s8 & 3;
    const int* pid = dirp ? pprev : pnext;
    const unsigned char* xb = (const unsigned char*)xbf;

    const int G = (int)gridDim.x;
    const int tiles = (Nn + 63) >> 6;

    uint4 q0a, q0b, q1a, q1b;
    int4 idxA = {0, 0, 0, 0}, idxB;
    { int gn = blockIdx.x * 64 + rg; if (gn < Nn) idxA = *(const int4*)(pid + (size_t)4 * gn); }

    for (int t = blockIdx.x; t < tiles; t += G) {
        const int base = t * 64;
        // stage X tile (16KB, linear from pre-swizzled xbf)
        {
            size_t xg = (size_t)base * 256u + (unsigned)(wid * 2048) + (unsigned)(lane * 16);
            __builtin_amdgcn_global_load_lds((const AS1 unsigned int*)(xb + xg),
                (AS3 unsigned int*)(lds + 32768u + (unsigned)(wid * 2048)), 16, 0, 0);
            __builtin_amdgcn_global_load_lds((const AS1 unsigned int*)(xb + xg + 1024),
                (AS3 unsigned int*)(lds + 32768u + (unsigned)(wid * 2048) + 1024u), 16, 0, 0);
        }
        // gather both neighbor fp8 rows: 32B from each (2x16B)
        {
            const unsigned char* r0 = xq + (size_t)idxA.y * 128u + (unsigned)(pg * 32);
            const unsigned char* r1 = xq + (size_t)idxA.w * 128u + (unsigned)(pg * 32);
            q0a = *(const uint4*)(r0);
            q0b = *(const uint4*)(r0 + 16);
            q1a = *(const uint4*)(r1);
            q1b = *(const uint4*)(r1 + 16);
        }
        __builtin_amdgcn_sched_barrier(0);
        // prefetch next tile's indices (stays outstanding across vmcnt(1))
        idxB = (int4){0, 0, 0, 0};
        {
            int gn = (t + G) * 64 + rg;
            if (t + G < tiles && gn < Nn) idxB = *(const int4*)(pid + (size_t)4 * gn);
        }
        __builtin_amdgcn_sched_barrier(0);
        asm volatile("s_waitcnt vmcnt(1)" ::: "memory");
        __builtin_amdgcn_sched_barrier(0);
        // dequant + sum -> S (bf16, swizzled)
        {
            unsigned char* Sd = lds + (unsigned)(rg * 512 + dirp * 256);
            unsigned swd = ((unsigned)(rg & 15)) << 4;
            uint2 e0, e1;
            uint4 d;
            e0 = sum4fp8(q0a.x, q1a.x); e1 = sum4fp8(q0a.y, q1a.y);
            d.x = e0.x; d.y = e0.y; d.z = e1.x; d.w = e1.y;
            *(uint4*)(Sd + (((unsigned)(pg * 64 + 0)) ^ swd)) = d;
            e0 = sum4fp8(q0a.z, q1a.z); e1 = sum4fp8(q0a.w, q1a.w);
            d.x = e0.x; d.y = e0.y; d.z = e1.x; d.w = e1.y;
            *(uint4*)(Sd + (((unsigned)(pg * 64 + 16)) ^ swd)) = d;
            e0 = sum4fp8(q0b.x, q1b.x); e1 = sum4fp8(q0b.y, q1b.y);
            d.x = e0.x; d.y = e0.y; d.z = e1.x; d.w = e1.y;
            *(uint4*)(Sd + (((unsigned)(pg * 64 + 32)) ^ swd)) = d;
            e0 = sum4fp8(q0b.z, q1b.z); e1 = sum4fp8(q0b.w, q1b.w);
            d.x = e0.x; d.y = e0.y; d.z = e1.x; d.w = e1.y;
            *(uint4*)(Sd + (((unsigned)(pg * 64 + 48)) ^ swd)) = d;
        }
        asm volatile("s_waitcnt lgkmcnt(0)" ::: "memory");
        __builtin_amdgcn_sched_barrier(0);
        __builtin_amdgcn_s_barrier();

        // GEMM1: 64 rows x wave's 16 cols
        f32x4 acc1[4];
#pragma unroll
        for (int m = 0; m < 4; m++) acc1[m] = (f32x4){bb, bb, bb, bb};
#pragma unroll
        for (int kk = 0; kk < 8; kk++) {
            unsigned ko = ((unsigned)(kk * 64 + kq * 16)) ^ rs;
            bf16x8 a0 = *(const bf16x8*)(lds + (unsigned)(0 * 16 + col0) * 512u + ko);
            bf16x8 a1 = *(const bf16x8*)(lds + (unsigned)(1 * 16 + col0) * 512u + ko);
            bf16x8 a2 = *(const bf16x8*)(lds + (unsigned)(2 * 16 + col0) * 512u + ko);
            bf16x8 a3 = *(const bf16x8*)(lds + (unsigned)(3 * 16 + col0) * 512u + ko);
            acc1[0] = __builtin_amdgcn_mfma_f32_16x16x32_bf16(a0, b1[kk], acc1[0], 0, 0, 0);
            acc1[1] = __builtin_amdgcn_mfma_f32_16x16x32_bf16(a1, b1[kk], acc1[1], 0, 0, 0);
            acc1[2] = __builtin_amdgcn_mfma_f32_16x16x32_bf16(a2, b1[kk], acc1[2], 0, 0, 0);
            acc1[3] = __builtin_amdgcn_mfma_f32_16x16x32_bf16(a3, b1[kk], acc1[3], 0, 0, 0);
        }
        // epi1: + x, relu, BN -> a_out (bf16 swizzled rows, nontemporal)
        {
            const unsigned char* X = lds + 32768u;
#pragma unroll
            for (int m = 0; m < 4; m++) {
#pragma unroll
                for (int i = 0; i < 4; i++) {
                    int r = m * 16 + kq * 4 + i;
                    int grow = base + r;
                    if (grow < Nn) {
                        unsigned sw = ((unsigned)(r & 15)) << 4;
                        unsigned co = ((unsigned)(f * 2)) ^ sw;
                        float xv = bf2f(*(const unsigned short*)(X + (unsigned)r * 256u + co));
                        float v = acc1[m][i] + xv;
                        v = fmaxf(v, 0.f) * sc + sh;
                        __builtin_nontemporal_store(
                            f2bf(v),
                            (unsigned short*)((unsigned char*)a_out + (size_t)grow * 256u + co));
                    }
                }
            }
        }
        __builtin_amdgcn_s_barrier();   // S/X reuse safety
        idxA = idxB;
    }
}

// ---------------- kB: [a|x] @ B2 (sparse, in regs) + GRU -> out, streaming dbuf ----------------
// LDS: buf p at p*32768: A 16K + X 16K
__attribute__((amdgpu_waves_per_eu(2, 2)))
__global__ __launch_bounds__(512) void k_g2_gru(
    const unsigned short* __restrict__ a_in, const unsigned short* __restrict__ xbf,
    const unsigned short* __restrict__ bt2p, const float* __restrict__ bias2,
    float* __restrict__ out, int Nn)
{
    __shared__ __align__(16) unsigned char lds[65536];
    const int tid = threadIdx.x, wid = tid >> 6, lane = tid & 63;
    const int col0 = lane & 15, kq = lane >> 4;
    const unsigned int rs = (unsigned)col0 << 4;

    // B2 sparse fragments: 96 regs, pinned
    const unsigned char* bt2b = (const unsigned char*)bt2p;
    bf16x8 b2z[8], b2r[8], b2xh[4], b2rh[4];
#pragma unroll
    for (int kk = 0; kk < 8; kk++) {
        b2z[kk] = *(const bf16x8*)(bt2b + (unsigned)(wid * 64 + 0 + col0) * 512u + (((unsigned)(kk * 64 + kq * 16)) ^ rs));
        b2r[kk] = *(const bf16x8*)(bt2b + (unsigned)(wid * 64 + 16 + col0) * 512u + (((unsigned)(kk * 64 + kq * 16)) ^ rs));
    }
#pragma unroll
    for (int kk = 0; kk < 4; kk++) {
        b2xh[kk] = *(const bf16x8*)(bt2b + (unsigned)(wid * 64 + 32 + col0) * 512u + (((unsigned)(kk * 64 + kq * 16)) ^ rs));
        b2rh[kk] = *(const bf16x8*)(bt2b + (unsigned)(wid * 64 + 48 + col0) * 512u + (((unsigned)((kk + 4) * 64 + kq * 16)) ^ rs));
    }
#pragma unroll
    for (int kk = 0; kk < 8; kk++) {
        asm volatile("" : "+v"(b2z[kk]));
        asm volatile("" : "+v"(b2r[kk]));
    }
#pragma unroll
    for (int kk = 0; kk < 4; kk++) {
        asm volatile("" : "+v"(b2xh[kk]));
        asm volatile("" : "+v"(b2rh[kk]));
    }

    const int f = wid * 16 + col0;
    const float cz = bias2[f], cr = bias2[128 + f], cxh = bias2[256 + f], crh = bias2[384 + f];

    const unsigned char* aB = (const unsigned char*)a_in;
    const unsigned char* xB = (const unsigned char*)xbf;
    const int G = (int)gridDim.x;
    const int tiles = (Nn + 63) >> 6;

#define STAGE2(tt, pp) do {                                                                  \
    size_t g_ = (size_t)(tt) * 16384u + (unsigned)(wid * 2048) + (unsigned)(lane * 16);      \
    unsigned o_ = (unsigned)(pp) * 32768u + (unsigned)(wid * 2048);                          \
    __builtin_amdgcn_global_load_lds((const AS1 unsigned int*)(aB + g_),                     \
                                     (AS3 unsigned int*)(lds + o_), 16, 0, 0);               \
    __builtin_amdgcn_global_load_lds((const AS1 unsigned int*)(aB + g_ + 1024),              \
                                     (AS3 unsigned int*)(lds + o_ + 1024), 16, 0, 0);        \
    __builtin_amdgcn_global_load_lds((const AS1 unsigned int*)(xB + g_),                     \
                                     (AS3 unsigned int*)(lds + o_ + 16384u), 16, 0, 0);      \
    __builtin_amdgcn_global_load_lds((const AS1 unsigned int*)(xB + g_ + 1024),              \
                                     (AS3 unsigned int*)(lds + o_ + 16384u + 1024), 16, 0, 0);\
} while (0)

    // prologue
    STAGE2(blockIdx.x, 0);
    asm volatile("s_waitcnt vmcnt(0)" ::: "memory");
    __builtin_amdgcn_sched_barrier(0);
    __builtin_amdgcn_s_barrier();

    int p = 0;
    for (int t = blockIdx.x; t < tiles; t += G) {
        const int base = t * 64;
        // prefetch next tile (clamped -> constant vmem count)
        {
            int tn = t + G;
            int tc = (tn < tiles) ? tn : t;
            STAGE2(tc, p ^ 1);
        }
        const unsigned char* A_ = lds + (unsigned)p * 32768u;
        const unsigned char* X_ = lds + (unsigned)p * 32768u + 16384u;

#pragma unroll
        for (int half = 0; half < 2; half++) {
            f32x4 az[2], ar[2], axh[2], arh[2];
#pragma unroll
            for (int mm = 0; mm < 2; mm++) {
                az[mm]  = (f32x4){cz, cz, cz, cz};
                ar[mm]  = (f32x4){cr, cr, cr, cr};
                axh[mm] = (f32x4){cxh, cxh, cxh, cxh};
                arh[mm] = (f32x4){crh, crh, crh, crh};
            }
#pragma unroll
            for (int kk = 0; kk < 8; kk++) {
                bf16x8 a2f[2];
#pragma unroll
                for (int mm = 0; mm < 2; mm++) {
                    int m = half * 2 + mm;
                    if (kk < 4)
                        a2f[mm] = *(const bf16x8*)(A_ + (unsigned)(m * 16 + col0) * 256u +
                                                   (((unsigned)(kk * 64 + kq * 16)) ^ rs));
                    else
                        a2f[mm] = *(const bf16x8*)(X_ + (unsigned)(m * 16 + col0) * 256u +
                                                   (((unsigned)((kk - 4) * 64 + kq * 16)) ^ rs));
                }
#pragma unroll
                for (int mm = 0; mm < 2; mm++) {
                    az[mm] = __builtin_amdgcn_mfma_f32_16x16x32_bf16(a2f[mm], b2z[kk], az[mm], 0, 0, 0);
                    ar[mm] = __builtin_amdgcn_mfma_f32_16x16x32_bf16(a2f[mm], b2r[kk], ar[mm], 0, 0, 0);
                    if (kk < 4)
                        axh[mm] = __builtin_amdgcn_mfma_f32_16x16x32_bf16(a2f[mm], b2xh[kk], axh[mm], 0, 0, 0);
                    else
                        arh[mm] = __builtin_amdgcn_mfma_f32_16x16x32_bf16(a2f[mm], b2rh[kk - 4], arh[mm], 0, 0, 0);
                }
            }
            // GRU epilogue for this half
#pragma unroll
            for (int mm = 0; mm < 2; mm++) {
                int m = half * 2 + mm;
#pragma unroll
                for (int i = 0; i < 4; i++) {
                    int r = m * 16 + kq * 4 + i;
                    int grow = base + r;
                    if (grow < Nn) {
                        float z  = __builtin_amdgcn_rcpf(1.f + __expf(-az[mm][i]));
                        float rr = __builtin_amdgcn_rcpf(1.f + __expf(-ar[mm][i]));
                        float u  = axh[mm][i] + rr * arh[mm][i];
                        float th = 1.f - 2.f * __builtin_amdgcn_rcpf(__expf(2.f * u) + 1.f);
                        unsigned sw = ((unsigned)(r & 15)) << 4;
                        float xv = bf2f(*(const unsigned short*)(X_ + (unsigned)r * 256u +
                                                                 (((unsigned)(f * 2)) ^ sw)));
                        __builtin_nontemporal_store(th + z * (xv - th),
                                                    out + (size_t)grow * FDIM + f);
                    }
                }
            }
        }
        // drain this iter's 4 stage loads (16 newer out-stores stay in flight)
        asm volatile("s_waitcnt vmcnt(16) lgkmcnt(0)" ::: "memory");
        __builtin_amdgcn_sched_barrier(0);
        __builtin_amdgcn_s_barrier();
        p ^= 1;
    }
#undef STAGE2
}

extern "C" void kernel_launch(void* const* d_in, const int* in_sizes, int n_in,
                              void* d_out, int out_size, void* d_ws, size_t ws_size,
                              hipStream_t stream)
{
    const float* x      = (const float*)d_in[0];
    const int*   pprev  = (const int*)d_in[1];
    const int*   pnext  = (const int*)d_in[2];
    const float* wNext  = (const float*)d_in[3];
    const float* wPrev  = (const float*)d_in[4];
    const float* b      = (const float*)d_in[5];
    const float* gk     = (const float*)d_in[6];
    const float* gr     = (const float*)d_in[7];
    const float* gb     = (const float*)d_in[8];
    const float* gamma  = (const float*)d_in[9];
    const float* beta   = (const float*)d_in[10];
    const float* mean   = (const float*)d_in[11];
    const float* var    = (const float*)d_in[12];
    float* out = (float*)d_out;
    const int Nn = in_sizes[0] / FDIM;

    // ws: xbf (N*256B) | a_ws (N*256B) | xq (N*128B) | bt1 (64KB) | bt2 (256KB) | bias2 | bnscale | bnshift
    unsigned char* ws = (unsigned char*)d_ws;
    unsigned short* xbf  = (unsigned short*)(ws + 0);
    unsigned short* a_ws = (unsigned short*)(ws + (size_t)Nn * 256u);
    unsigned char*  xq   = (unsigned char*)(ws + (size_t)Nn * 512u);
    size_t off_bt = (size_t)Nn * 640u;
    unsigned short* bt1   = (unsigned short*)(ws + off_bt);
    unsigned short* bt2   = (unsigned short*)(ws + off_bt + 65536);
    float* bias2          = (float*)(ws + off_bt + 327680);
    float* bnscale        = (float*)(ws + off_bt + 327680 + 2048);
    float* bnshift        = (float*)(ws + off_bt + 327680 + 2048 + 512);

    prep_kernel<<<643, 256, 0, stream>>>(wNext, wPrev, gk, gr, gb, gamma, beta, mean, var,
                                         bt1, bt2, bias2, bnscale, bnshift);
    x_convert<<<2048, 256, 0, stream>>>(x, xbf, xq, Nn);
    k_gather_g1<<<768, 512, 0, stream>>>(xbf, xq, pprev, pnext, bt1, b, bnscale, bnshift, a_ws, Nn);
    k_g2_gru<<<256, 512, 0, stream>>>(a_ws, xbf, bt2, bias2, out, Nn);
}